// Round 7
// baseline (10328.211 us; speedup 1.0000x reference)
//
#include <hip/hip_runtime.h>

#define T_STEPS 512
#define BB 64
#define CC 256
#define HH 1024
#define TBROWS (T_STEPS*BB)      // 32768
#define BH (BB*HH)               // 65536

typedef unsigned short u16;
typedef __bf16 bf16_t;
typedef bf16_t bf16x8 __attribute__((ext_vector_type(8)));
typedef float f32x4 __attribute__((ext_vector_type(4)));

__device__ __forceinline__ f32x4 mfma16(bf16x8 a, bf16x8 b, f32x4 c) {
  return __builtin_amdgcn_mfma_f32_16x16x32_bf16(a, b, c, 0, 0, 0);
}

__device__ __forceinline__ u16 f2bf(float f) {
  unsigned u = __float_as_uint(f);
  u += 0x7fffu + ((u >> 16) & 1u);
  return (u16)(u >> 16);
}
__device__ __forceinline__ float bf2f(u16 h) {
  return __uint_as_float(((unsigned)h) << 16);
}

// coherent 8B store: write-through to LLC (agent coherence point), cross-XCD safe
__device__ __forceinline__ void store_coh8(void* p, uint2 v) {
  asm volatile("global_store_dwordx2 %0, %1, off sc0 sc1" :: "v"(p), "v"(v) : "memory");
}

__global__ void sentinel_kernel(float* o, float v) { o[0] = v; }

// ---------------- split fp32 -> (hi, lo) bf16 ----------------
__global__ __launch_bounds__(256) void split_kernel(const float* __restrict__ src,
                                                    u16* __restrict__ hi,
                                                    u16* __restrict__ lo, int n4) {
  int i = blockIdx.x * 256 + threadIdx.x;
  if (i >= n4) return;
  const float4 v = ((const float4*)src)[i];
  float vv[4] = {v.x, v.y, v.z, v.w};
  u16 h[4], l[4];
#pragma unroll
  for (int j = 0; j < 4; ++j) {
    h[j] = f2bf(vv[j]);
    l[j] = f2bf(vv[j] - bf2f(h[j]));
  }
  uint2 ho, lu;
  ho.x = (unsigned)h[0] | ((unsigned)h[1] << 16);
  ho.y = (unsigned)h[2] | ((unsigned)h[3] << 16);
  lu.x = (unsigned)l[0] | ((unsigned)l[1] << 16);
  lu.y = (unsigned)l[2] | ((unsigned)l[3] << 16);
  ((uint2*)hi)[i] = ho;
  ((uint2*)lo)[i] = lu;
}

__global__ __launch_bounds__(256) void add_bias_kernel(const float* __restrict__ a,
                                                       const float* __restrict__ b,
                                                       float* __restrict__ o, int n) {
  int i = blockIdx.x * 256 + threadIdx.x;
  if (i < n) o[i] = a[i] + b[i];
}

// ---------------- split-bf16 3-pass GEMM: C[M,N] = A[M,K] @ W[N,K]^T + bias ----------------
__global__ __launch_bounds__(256) void gemm3(const u16* __restrict__ Ahi, const u16* __restrict__ Alo,
                                             const u16* __restrict__ Whi, const u16* __restrict__ Wlo,
                                             const float* __restrict__ bias,
                                             float* __restrict__ Cd,
                                             int M, int N, int K) {
  __shared__ u16 As[2][128][48];
  __shared__ u16 Bs[2][128][48];
  const int tid = threadIdx.x;
  const int nblk = N >> 7;
  const int mb = blockIdx.x / nblk;
  const int nb = blockIdx.x % nblk;
  const int m0 = mb << 7, n0 = nb << 7;
  const int lane = tid & 63, wave = tid >> 6;
  const int wm = (wave >> 1) * 64, wn = (wave & 1) * 64;
  const int fr = lane & 15, kg = lane >> 4;

  f32x4 acc[4][4];
#pragma unroll
  for (int i = 0; i < 4; ++i)
#pragma unroll
    for (int j = 0; j < 4; ++j) acc[i][j] = (f32x4){0.f, 0.f, 0.f, 0.f};

  const int sr = tid >> 1;        // 0..127
  const int sk = (tid & 1) * 16;  // 0 or 16

  for (int k0 = 0; k0 < K; k0 += 32) {
    __syncthreads();
    const size_t aoff = (size_t)(m0 + sr) * K + k0 + sk;
    *(uint4*)&As[0][sr][sk]     = *(const uint4*)(Ahi + aoff);
    *(uint4*)&As[0][sr][sk + 8] = *(const uint4*)(Ahi + aoff + 8);
    *(uint4*)&As[1][sr][sk]     = *(const uint4*)(Alo + aoff);
    *(uint4*)&As[1][sr][sk + 8] = *(const uint4*)(Alo + aoff + 8);
    const size_t woff = (size_t)(n0 + sr) * K + k0 + sk;
    *(uint4*)&Bs[0][sr][sk]     = *(const uint4*)(Whi + woff);
    *(uint4*)&Bs[0][sr][sk + 8] = *(const uint4*)(Whi + woff + 8);
    *(uint4*)&Bs[1][sr][sk]     = *(const uint4*)(Wlo + woff);
    *(uint4*)&Bs[1][sr][sk + 8] = *(const uint4*)(Wlo + woff + 8);
    __syncthreads();

    bf16x8 ah[4], al[4], bh[4], bl[4];
#pragma unroll
    for (int i = 0; i < 4; ++i) {
      ah[i] = *(const bf16x8*)&As[0][wm + i * 16 + fr][kg * 8];
      al[i] = *(const bf16x8*)&As[1][wm + i * 16 + fr][kg * 8];
      bh[i] = *(const bf16x8*)&Bs[0][wn + i * 16 + fr][kg * 8];
      bl[i] = *(const bf16x8*)&Bs[1][wn + i * 16 + fr][kg * 8];
    }
#pragma unroll
    for (int i = 0; i < 4; ++i)
#pragma unroll
      for (int j = 0; j < 4; ++j) {
        acc[i][j] = mfma16(ah[i], bh[j], acc[i][j]);
        acc[i][j] = mfma16(ah[i], bl[j], acc[i][j]);
        acc[i][j] = mfma16(al[i], bh[j], acc[i][j]);
      }
  }

#pragma unroll
  for (int j = 0; j < 4; ++j) {
    const int n = n0 + wn + j * 16 + fr;
    const float bv = bias ? bias[n] : 0.f;
#pragma unroll
    for (int i = 0; i < 4; ++i) {
#pragma unroll
      for (int r = 0; r < 4; ++r) {
        const int m = m0 + wm + i * 16 + kg * 4 + r;
        Cd[(size_t)m * N + n] = acc[i][j][r] + bv;
      }
    }
  }
}

// ---------------- fused two-layer pipelined scan ----------------
// 128 WGs x 1024 threads (16 waves = 4 K-slices x 4 batch groups), all co-resident.
// wg<64: layer 0 (K=1024). wg>=64: layer 1 (K=2048 = [W_ih1 | W_hh1]).
// r7 change: explicit batched register prefetch of h (L0: all 16 loads upfront;
// L1: rolling window of ~16-18 outstanding) to break the ~5-outstanding load
// serialization seen at VGPR_Count=64 in r6.
__global__ __launch_bounds__(1024) void rnn_fused(
    const u16* __restrict__ whh0_hi, const u16* __restrict__ whh0_lo,
    const u16* __restrict__ wih1_hi, const u16* __restrict__ wih1_lo,
    const u16* __restrict__ whh1_hi, const u16* __restrict__ whh1_lo,
    const u16* __restrict__ cin_hi, const u16* __restrict__ cin_lo,    // [2*BH]
    u16* __restrict__ cout_hi, u16* __restrict__ cout_lo,              // [2*BH]
    const float* __restrict__ xw,                                      // [nsteps,B,H] (b0 included)
    const float* __restrict__ b1,                                      // [H] = b_ih1+b_hh1
    u16* __restrict__ y0hi, u16* __restrict__ y0lo,                    // [nsteps,B,H]
    u16* __restrict__ y1hi, u16* __restrict__ y1lo,                    // [nsteps,B,H]
    float* __restrict__ hlast0, float* __restrict__ hlast1,            // [B,H] f32
    int* __restrict__ flags0, int* __restrict__ flags1,                // [nsteps][64] each
    int nsteps) {
  __shared__ u16 Ws[2][16][2048];   // 128 KB (L0 uses k<1024 of each row)
  __shared__ f32x4 red[3][4][64];   // 12 KB cross-wave K-reduction

  const int wg = blockIdx.x;
  const bool isL1 = wg >= 64;
  const int wl = isL1 ? wg - 64 : wg;
  const int n0 = wl << 4;
  const int tid = threadIdx.x;
  const int lane = tid & 63, wave = tid >> 6;
  const int q = wave >> 2;          // K-slice index
  const int g = wave & 3;           // batch group
  const int fr = lane & 15, kg = lane >> 4;

  // swizzled LDS address: row stride 4096B, XOR 16B slot with (row&7)
  auto wsp = [&](int hl, int r, int cbyte) -> u16* {
    return (u16*)((char*)Ws + (size_t)(hl * 16 + r) * 4096 + (cbyte ^ ((r & 7) << 4)));
  };

  if (!isL1) {  // stage 64KB: [2][16][1024] from whh0
#pragma unroll
    for (int j = 0; j < 4; ++j) {
      const int off = tid * 64 + j * 16;
      const int plane = off >> 15;
      const int row = (off >> 11) & 15;
      const int cbyte = off & 2047;
      const u16* src = (plane ? whh0_lo : whh0_hi) + (size_t)(n0 + row) * HH + (cbyte >> 1);
      *(uint4*)wsp(plane, row, cbyte) = *(const uint4*)src;
    }
  } else {      // stage 128KB: [2][16][2048], k<1024 from wih1, k>=1024 from whh1
#pragma unroll
    for (int j = 0; j < 8; ++j) {
      const int off = tid * 128 + j * 16;
      const int plane = off >> 16;
      const int row = (off >> 12) & 15;
      const int cbyte = off & 4095;
      const int k = cbyte >> 1;
      const u16* src = (k < 1024)
          ? ((plane ? wih1_lo : wih1_hi) + (size_t)(n0 + row) * HH + k)
          : ((plane ? whh1_lo : whh1_hi) + (size_t)(n0 + row) * HH + (k - 1024));
      *(uint4*)wsp(plane, row, cbyte) = *(const uint4*)src;
    }
  }
  __syncthreads();

  const int b = (g << 4) + fr;                   // batch (B-operand col, output col)
  const int co = n0 + (kg << 2);                 // output column base (4 contiguous)
  const int koff = isL1 ? ((q < 2) ? q * 512 : (q - 2) * 512) : q * 256;  // src h col base
  const size_t hoff = (size_t)b * HH + koff + (kg << 3);
  const int cb0 = isL1 ? q * 1024 : q * 512;     // LDS row byte base of this K-slice
  float4 bias4;
  if (isL1 && q == 0) bias4 = *(const float4*)(b1 + co);

  for (int t = 0; t < nsteps; ++t) {
    const size_t obase = (size_t)t * BH;
    float4 xwv;
    if (!isL1 && q == 0) xwv = *(const float4*)(xw + obase + (size_t)b * HH + co);

    // ---- per-wave fine-grained poll ----
    if (!isL1) {
      if (t > 0 && lane < 16) {
        const int* f = flags0 + (t - 1) * 64 + 16 * q + lane;
        while (__hip_atomic_load(f, __ATOMIC_RELAXED, __HIP_MEMORY_SCOPE_AGENT) == 0)
          __builtin_amdgcn_s_sleep(1);
      }
    } else if (q < 2) {
      if (lane < 32) {
        const int* f = flags0 + t * 64 + 32 * q + lane;
        while (__hip_atomic_load(f, __ATOMIC_RELAXED, __HIP_MEMORY_SCOPE_AGENT) == 0)
          __builtin_amdgcn_s_sleep(1);
      }
    } else {
      if (t > 0 && lane < 32) {
        const int* f = flags1 + (t - 1) * 64 + 32 * (q - 2) + lane;
        while (__hip_atomic_load(f, __ATOMIC_RELAXED, __HIP_MEMORY_SCOPE_AGENT) == 0)
          __builtin_amdgcn_s_sleep(1);
      }
    }
    __atomic_signal_fence(__ATOMIC_ACQUIRE);  // compiler barrier; HW coherent via first-touch

    // ---- source pointers for this wave's K-slice ----
    const u16 *pb, *pl;
    if (!isL1) {
      const u16* hh = (t == 0) ? cin_hi : (y0hi + (size_t)(t - 1) * BH);
      const u16* hl = (t == 0) ? cin_lo : (y0lo + (size_t)(t - 1) * BH);
      pb = hh + hoff; pl = hl + hoff;
    } else if (q < 2) {
      pb = y0hi + obase + hoff; pl = y0lo + obase + hoff;
    } else {
      const u16* hh = (t == 0) ? (cin_hi + BH) : (y1hi + (size_t)(t - 1) * BH);
      const u16* hl = (t == 0) ? (cin_lo + BH) : (y1lo + (size_t)(t - 1) * BH);
      pb = hh + hoff; pl = hl + hoff;
    }

    f32x4 accs[3][2];
#pragma unroll
    for (int i = 0; i < 3; ++i)
#pragma unroll
      for (int j = 0; j < 2; ++j) accs[i][j] = (f32x4){0.f, 0.f, 0.f, 0.f};

    if (!isL1) {
      // all 16 loads upfront (64 VGPR), then MFMA off registers
      bf16x8 hb[8], hl8[8];
#pragma unroll
      for (int kc = 0; kc < 8; ++kc) {
        hb[kc]  = *(const bf16x8*)(pb + kc * 32);
        hl8[kc] = *(const bf16x8*)(pl + kc * 32);
      }
#pragma unroll
      for (int kc = 0; kc < 8; ++kc) {
        const int cb = cb0 + kc * 64 + kg * 16;
        bf16x8 wh = *(const bf16x8*)wsp(0, fr, cb);
        bf16x8 wl = *(const bf16x8*)wsp(1, fr, cb);
        const int s = kc & 1;
        accs[0][s] = mfma16(wh, hb[kc],  accs[0][s]);
        accs[1][s] = mfma16(wh, hl8[kc], accs[1][s]);
        accs[2][s] = mfma16(wl, hb[kc],  accs[2][s]);
      }
    } else {
      // rolling window: preload kc 0..7, issue kc+8 before consuming kc
      bf16x8 hb[16], hl8[16];
#pragma unroll
      for (int kc = 0; kc < 8; ++kc) {
        hb[kc]  = *(const bf16x8*)(pb + kc * 32);
        hl8[kc] = *(const bf16x8*)(pl + kc * 32);
      }
#pragma unroll
      for (int kc = 0; kc < 16; ++kc) {
        if (kc < 8) {
          hb[kc + 8]  = *(const bf16x8*)(pb + (kc + 8) * 32);
          hl8[kc + 8] = *(const bf16x8*)(pl + (kc + 8) * 32);
        }
        const int cb = cb0 + kc * 64 + kg * 16;
        bf16x8 wh = *(const bf16x8*)wsp(0, fr, cb);
        bf16x8 wl = *(const bf16x8*)wsp(1, fr, cb);
        const int s = kc & 1;
        accs[0][s] = mfma16(wh, hb[kc],  accs[0][s]);
        accs[1][s] = mfma16(wh, hl8[kc], accs[1][s]);
        accs[2][s] = mfma16(wl, hb[kc],  accs[2][s]);
      }
    }
    f32x4 accv = (accs[0][0] + accs[0][1]) + (accs[1][0] + accs[1][1]) +
                 (accs[2][0] + accs[2][1]);

    if (q != 0) red[q - 1][g][lane] = accv;
    __syncthreads();                              // barrier B

    if (q == 0) {
      accv = accv + red[0][g][lane] + red[1][g][lane] + red[2][g][lane];
      u16 hbv[4], lbv[4];
      float hv[4];
#pragma unroll
      for (int r = 0; r < 4; ++r) {
        const float s = accv[r] + (isL1 ? ((const float*)&bias4)[r] : ((const float*)&xwv)[r]);
        hv[r] = tanhf(s);
        hbv[r] = f2bf(hv[r]);
        lbv[r] = f2bf(hv[r] - bf2f(hbv[r]));
      }
      const size_t oi = obase + (size_t)b * HH + co;
      uint2 hp, lp;
      hp.x = (unsigned)hbv[0] | ((unsigned)hbv[1] << 16);
      hp.y = (unsigned)hbv[2] | ((unsigned)hbv[3] << 16);
      lp.x = (unsigned)lbv[0] | ((unsigned)lbv[1] << 16);
      lp.y = (unsigned)lbv[2] | ((unsigned)lbv[3] << 16);
      if (!isL1) { store_coh8(y0hi + oi, hp); store_coh8(y0lo + oi, lp); }
      else       { store_coh8(y1hi + oi, hp); store_coh8(y1lo + oi, lp); }
      if (t == nsteps - 1) {
        const size_t ci = (size_t)b * HH + co;
        const size_t cofs = isL1 ? (size_t)BH : 0;
        *(uint2*)(cout_hi + cofs + ci) = hp;
        *(uint2*)(cout_lo + cofs + ci) = lp;
        *(float4*)((isL1 ? hlast1 : hlast0) + ci) = (float4){hv[0], hv[1], hv[2], hv[3]};
      }
      asm volatile("s_waitcnt vmcnt(0)" ::: "memory");  // y stores reached LLC
    }
    __syncthreads();                              // barrier C
    if (tid == 0) {
      int* fp = (isL1 ? flags1 : flags0) + t * 64 + wl;
      __hip_atomic_store(fp, 1, __ATOMIC_RELEASE, __HIP_MEMORY_SCOPE_AGENT);
    }
  }
}

// ---------------- host ----------------
struct Ptrs {
  u16 *wih0_hi, *wih0_lo, *whh0_hi, *whh0_lo, *wih1_hi, *wih1_lo,
      *whh1_hi, *whh1_lo, *wdec_hi, *wdec_lo;
  float *b0, *b1;
  u16 *carA_hi, *carA_lo, *carB_hi, *carB_lo;  // [2*BH] each
  int* flags;                                   // [2*T_STEPS*64]
  u16 *x_hi, *x_lo;                             // [CT*BB*CC]
  float* xw;                                    // [CT*BH]
  u16 *y0_hi, *y0_lo, *y1_hi, *y1_lo;           // [CT*BH]
  size_t total;
};

static Ptrs make_plan(char* base, int CT) {
  Ptrs p;
  size_t off = 0;
  auto take = [&](size_t bytes) -> char* {
    off = (off + 255) & ~(size_t)255;
    char* q = base + off;
    off += bytes;
    return q;
  };
  p.wih0_hi = (u16*)take((size_t)HH * CC * 2);
  p.wih0_lo = (u16*)take((size_t)HH * CC * 2);
  p.whh0_hi = (u16*)take((size_t)HH * HH * 2);
  p.whh0_lo = (u16*)take((size_t)HH * HH * 2);
  p.wih1_hi = (u16*)take((size_t)HH * HH * 2);
  p.wih1_lo = (u16*)take((size_t)HH * HH * 2);
  p.whh1_hi = (u16*)take((size_t)HH * HH * 2);
  p.whh1_lo = (u16*)take((size_t)HH * HH * 2);
  p.wdec_hi = (u16*)take((size_t)CC * HH * 2);
  p.wdec_lo = (u16*)take((size_t)CC * HH * 2);
  p.b0      = (float*)take((size_t)HH * 4);
  p.b1      = (float*)take((size_t)HH * 4);
  p.carA_hi = (u16*)take((size_t)2 * BH * 2);
  p.carA_lo = (u16*)take((size_t)2 * BH * 2);
  p.carB_hi = (u16*)take((size_t)2 * BH * 2);
  p.carB_lo = (u16*)take((size_t)2 * BH * 2);
  p.flags   = (int*)take((size_t)2 * T_STEPS * 64 * 4);
  p.x_hi    = (u16*)take((size_t)CT * BB * CC * 2);
  p.x_lo    = (u16*)take((size_t)CT * BB * CC * 2);
  p.xw      = (float*)take((size_t)CT * BH * 4);
  p.y0_hi   = (u16*)take((size_t)CT * BH * 2);
  p.y0_lo   = (u16*)take((size_t)CT * BH * 2);
  p.y1_hi   = (u16*)take((size_t)CT * BH * 2);
  p.y1_lo   = (u16*)take((size_t)CT * BH * 2);
  p.total   = off;
  return p;
}

extern "C" void kernel_launch(void* const* d_in, const int* in_sizes, int n_in,
                              void* d_out, int out_size, void* d_ws, size_t ws_size,
                              hipStream_t stream) {
  (void)in_sizes; (void)n_in; (void)out_size;
  const float* x     = (const float*)d_in[0];
  const float* h0    = (const float*)d_in[1];
  const float* w_ih0 = (const float*)d_in[2];
  const float* w_hh0 = (const float*)d_in[3];
  const float* b_ih0 = (const float*)d_in[4];
  const float* b_hh0 = (const float*)d_in[5];
  const float* w_ih1 = (const float*)d_in[6];
  const float* w_hh1 = (const float*)d_in[7];
  const float* b_ih1 = (const float*)d_in[8];
  const float* b_hh1 = (const float*)d_in[9];
  const float* w_dec = (const float*)d_in[10];
  const float* b_dec = (const float*)d_in[11];
  float* out = (float*)d_out;

  // largest chunk CT whose plan fits ws_size
  int CT = T_STEPS;
  Ptrs P = make_plan((char*)d_ws, CT);
  while (P.total > ws_size && CT > 8) {
    CT >>= 1;
    P = make_plan((char*)d_ws, CT);
  }
  if (P.total > ws_size) {
    sentinel_kernel<<<1, 1, 0, stream>>>(out, (float)ws_size);
    return;
  }
  const int NCH = T_STEPS / CT;

  hipMemsetAsync(P.flags, 0, (size_t)2 * T_STEPS * 64 * 4, stream);

  // one-time weight/bias/h0 prep
  split_kernel<<<HH * CC / 1024, 256, 0, stream>>>(w_ih0, P.wih0_hi, P.wih0_lo, HH * CC / 4);
  split_kernel<<<HH * HH / 1024, 256, 0, stream>>>(w_hh0, P.whh0_hi, P.whh0_lo, HH * HH / 4);
  split_kernel<<<HH * HH / 1024, 256, 0, stream>>>(w_ih1, P.wih1_hi, P.wih1_lo, HH * HH / 4);
  split_kernel<<<HH * HH / 1024, 256, 0, stream>>>(w_hh1, P.whh1_hi, P.whh1_lo, HH * HH / 4);
  split_kernel<<<CC * HH / 1024, 256, 0, stream>>>(w_dec, P.wdec_hi, P.wdec_lo, CC * HH / 4);
  split_kernel<<<2 * BH / 1024, 256, 0, stream>>>(h0, P.carA_hi, P.carA_lo, 2 * BH / 4);
  add_bias_kernel<<<HH / 256, 256, 0, stream>>>(b_ih0, b_hh0, P.b0, HH);
  add_bias_kernel<<<HH / 256, 256, 0, stream>>>(b_ih1, b_hh1, P.b1, HH);

  float* hlast0 = out + (size_t)TBROWS * CC;
  float* hlast1 = hlast0 + BH;

  for (int c = 0; c < NCH; ++c) {
    const int t0 = c * CT;
    const u16* cin_hi = (c & 1) ? P.carB_hi : P.carA_hi;
    const u16* cin_lo = (c & 1) ? P.carB_lo : P.carA_lo;
    u16* cout_hi = (c & 1) ? P.carA_hi : P.carB_hi;
    u16* cout_lo = (c & 1) ? P.carA_lo : P.carB_lo;

    // split x chunk
    split_kernel<<<CT * 16, 256, 0, stream>>>(x + (size_t)t0 * BB * CC, P.x_hi, P.x_lo,
                                              CT * BB * CC / 4);
    // layer-0 input projection: [CT*64, 256] @ [1024,256]^T -> xw (b0 folded in)
    gemm3<<<(CT * BB / 128) * (HH / 128), 256, 0, stream>>>(P.x_hi, P.x_lo, P.wih0_hi, P.wih0_lo,
                                                            P.b0, P.xw, CT * BB, HH, CC);
    // fused two-layer pipelined scan (replaces scan0 + xw1 GEMM + scan1)
    rnn_fused<<<128, 1024, 0, stream>>>(
        P.whh0_hi, P.whh0_lo, P.wih1_hi, P.wih1_lo, P.whh1_hi, P.whh1_lo,
        cin_hi, cin_lo, cout_hi, cout_lo, P.xw, P.b1,
        P.y0_hi, P.y0_lo, P.y1_hi, P.y1_lo, hlast0, hlast1,
        P.flags + (size_t)t0 * 64, P.flags + (size_t)(T_STEPS + t0) * 64, CT);
    // decoder: [CT*64,1024] @ [256,1024]^T -> out chunk
    gemm3<<<(CT * BB / 128) * (CC / 128), 256, 0, stream>>>(P.y1_hi, P.y1_lo, P.wdec_hi, P.wdec_lo,
                                                            b_dec, out + (size_t)t0 * BB * CC,
                                                            CT * BB, CC, HH);
  }
}

// Round 8
// 9805.275 us; speedup vs baseline: 1.0533x; 1.0533x over previous
//
#include <hip/hip_runtime.h>

#define T_STEPS 512
#define BB 64
#define CC 256
#define HH 1024
#define TBROWS (T_STEPS*BB)      // 32768
#define BH (BB*HH)               // 65536

typedef unsigned short u16;
typedef __bf16 bf16_t;
typedef bf16_t bf16x8 __attribute__((ext_vector_type(8)));
typedef float f32x4 __attribute__((ext_vector_type(4)));

__device__ __forceinline__ f32x4 mfma16(bf16x8 a, bf16x8 b, f32x4 c) {
  return __builtin_amdgcn_mfma_f32_16x16x32_bf16(a, b, c, 0, 0, 0);
}

__device__ __forceinline__ u16 f2bf(float f) {
  unsigned u = __float_as_uint(f);
  u += 0x7fffu + ((u >> 16) & 1u);
  return (u16)(u >> 16);
}
__device__ __forceinline__ float bf2f(u16 h) {
  return __uint_as_float(((unsigned)h) << 16);
}

// coherent 8B store: write-through to LLC (agent coherence point), cross-XCD safe
__device__ __forceinline__ void store_coh8(void* p, uint2 v) {
  asm volatile("global_store_dwordx2 %0, %1, off sc0 sc1" :: "v"(p), "v"(v) : "memory");
}

// poll an aggregate per-step counter until all 64 producer WGs checked in.
// whole wave polls one uniform address (1 line access per poll), long backoff.
__device__ __forceinline__ void poll_cnt(const int* c) {
  while (__hip_atomic_load(c, __ATOMIC_RELAXED, __HIP_MEMORY_SCOPE_AGENT) < 64)
    __builtin_amdgcn_s_sleep(2);
}

__global__ void sentinel_kernel(float* o, float v) { o[0] = v; }

// ---------------- split fp32 -> (hi, lo) bf16 ----------------
__global__ __launch_bounds__(256) void split_kernel(const float* __restrict__ src,
                                                    u16* __restrict__ hi,
                                                    u16* __restrict__ lo, int n4) {
  int i = blockIdx.x * 256 + threadIdx.x;
  if (i >= n4) return;
  const float4 v = ((const float4*)src)[i];
  float vv[4] = {v.x, v.y, v.z, v.w};
  u16 h[4], l[4];
#pragma unroll
  for (int j = 0; j < 4; ++j) {
    h[j] = f2bf(vv[j]);
    l[j] = f2bf(vv[j] - bf2f(h[j]));
  }
  uint2 ho, lu;
  ho.x = (unsigned)h[0] | ((unsigned)h[1] << 16);
  ho.y = (unsigned)h[2] | ((unsigned)h[3] << 16);
  lu.x = (unsigned)l[0] | ((unsigned)l[1] << 16);
  lu.y = (unsigned)l[2] | ((unsigned)l[3] << 16);
  ((uint2*)hi)[i] = ho;
  ((uint2*)lo)[i] = lu;
}

__global__ __launch_bounds__(256) void add_bias_kernel(const float* __restrict__ a,
                                                       const float* __restrict__ b,
                                                       float* __restrict__ o, int n) {
  int i = blockIdx.x * 256 + threadIdx.x;
  if (i < n) o[i] = a[i] + b[i];
}

// ---------------- split-bf16 3-pass GEMM: C[M,N] = A[M,K] @ W[N,K]^T + bias ----------------
__global__ __launch_bounds__(256) void gemm3(const u16* __restrict__ Ahi, const u16* __restrict__ Alo,
                                             const u16* __restrict__ Whi, const u16* __restrict__ Wlo,
                                             const float* __restrict__ bias,
                                             float* __restrict__ Cd,
                                             int M, int N, int K) {
  __shared__ u16 As[2][128][48];
  __shared__ u16 Bs[2][128][48];
  const int tid = threadIdx.x;
  const int nblk = N >> 7;
  const int mb = blockIdx.x / nblk;
  const int nb = blockIdx.x % nblk;
  const int m0 = mb << 7, n0 = nb << 7;
  const int lane = tid & 63, wave = tid >> 6;
  const int wm = (wave >> 1) * 64, wn = (wave & 1) * 64;
  const int fr = lane & 15, kg = lane >> 4;

  f32x4 acc[4][4];
#pragma unroll
  for (int i = 0; i < 4; ++i)
#pragma unroll
    for (int j = 0; j < 4; ++j) acc[i][j] = (f32x4){0.f, 0.f, 0.f, 0.f};

  const int sr = tid >> 1;        // 0..127
  const int sk = (tid & 1) * 16;  // 0 or 16

  for (int k0 = 0; k0 < K; k0 += 32) {
    __syncthreads();
    const size_t aoff = (size_t)(m0 + sr) * K + k0 + sk;
    *(uint4*)&As[0][sr][sk]     = *(const uint4*)(Ahi + aoff);
    *(uint4*)&As[0][sr][sk + 8] = *(const uint4*)(Ahi + aoff + 8);
    *(uint4*)&As[1][sr][sk]     = *(const uint4*)(Alo + aoff);
    *(uint4*)&As[1][sr][sk + 8] = *(const uint4*)(Alo + aoff + 8);
    const size_t woff = (size_t)(n0 + sr) * K + k0 + sk;
    *(uint4*)&Bs[0][sr][sk]     = *(const uint4*)(Whi + woff);
    *(uint4*)&Bs[0][sr][sk + 8] = *(const uint4*)(Whi + woff + 8);
    *(uint4*)&Bs[1][sr][sk]     = *(const uint4*)(Wlo + woff);
    *(uint4*)&Bs[1][sr][sk + 8] = *(const uint4*)(Wlo + woff + 8);
    __syncthreads();

    bf16x8 ah[4], al[4], bh[4], bl[4];
#pragma unroll
    for (int i = 0; i < 4; ++i) {
      ah[i] = *(const bf16x8*)&As[0][wm + i * 16 + fr][kg * 8];
      al[i] = *(const bf16x8*)&As[1][wm + i * 16 + fr][kg * 8];
      bh[i] = *(const bf16x8*)&Bs[0][wn + i * 16 + fr][kg * 8];
      bl[i] = *(const bf16x8*)&Bs[1][wn + i * 16 + fr][kg * 8];
    }
#pragma unroll
    for (int i = 0; i < 4; ++i)
#pragma unroll
      for (int j = 0; j < 4; ++j) {
        acc[i][j] = mfma16(ah[i], bh[j], acc[i][j]);
        acc[i][j] = mfma16(ah[i], bl[j], acc[i][j]);
        acc[i][j] = mfma16(al[i], bh[j], acc[i][j]);
      }
  }

#pragma unroll
  for (int j = 0; j < 4; ++j) {
    const int n = n0 + wn + j * 16 + fr;
    const float bv = bias ? bias[n] : 0.f;
#pragma unroll
    for (int i = 0; i < 4; ++i) {
#pragma unroll
      for (int r = 0; r < 4; ++r) {
        const int m = m0 + wm + i * 16 + kg * 4 + r;
        Cd[(size_t)m * N + n] = acc[i][j][r] + bv;
      }
    }
  }
}

// ---------------- fused two-layer pipelined scan ----------------
// 128 WGs x 1024 threads (16 waves = 4 K-slices x 4 batch groups), all co-resident.
// wg<64: layer 0 (K=1024). wg>=64: layer 1 (K=2048 = [W_ih1 | W_hh1]).
// r8 sync: per-step AGGREGATE counters (one atomicAdd per producer WG per step)
// replace 64 per-WG flags; ONE poller wave per dependency class polls the counter
// (uniform address, s_sleep(2) backoff) and publishes to an LDS gate; the other
// waves spin on LDS (no fabric traffic). Cuts global poll traffic ~16x vs r7.
__global__ __launch_bounds__(1024) void rnn_fused(
    const u16* __restrict__ whh0_hi, const u16* __restrict__ whh0_lo,
    const u16* __restrict__ wih1_hi, const u16* __restrict__ wih1_lo,
    const u16* __restrict__ whh1_hi, const u16* __restrict__ whh1_lo,
    const u16* __restrict__ cin_hi, const u16* __restrict__ cin_lo,    // [2*BH]
    u16* __restrict__ cout_hi, u16* __restrict__ cout_lo,              // [2*BH]
    const float* __restrict__ xw,                                      // [nsteps,B,H] (b0 included)
    const float* __restrict__ b1,                                      // [H] = b_ih1+b_hh1
    u16* __restrict__ y0hi, u16* __restrict__ y0lo,                    // [nsteps,B,H]
    u16* __restrict__ y1hi, u16* __restrict__ y1lo,                    // [nsteps,B,H]
    float* __restrict__ hlast0, float* __restrict__ hlast1,            // [B,H] f32
    int* __restrict__ cnt0, int* __restrict__ cnt1,                    // [nsteps] aggregate counters
    int nsteps) {
  __shared__ u16 Ws[2][16][2048];   // 128 KB (L0 uses k<1024 of each row)
  __shared__ f32x4 red[3][4][64];   // 12 KB cross-wave K-reduction
  __shared__ int gate[2];           // LDS release gates (step-encoded)

  const int wg = blockIdx.x;
  const bool isL1 = wg >= 64;
  const int wl = isL1 ? wg - 64 : wg;
  const int n0 = wl << 4;
  const int tid = threadIdx.x;
  const int lane = tid & 63, wave = tid >> 6;
  const int q = wave >> 2;          // K-slice index
  const int g = wave & 3;           // batch group
  const int fr = lane & 15, kg = lane >> 4;

  if (tid < 2) gate[tid] = 0;

  // swizzled LDS address: row stride 4096B, XOR 16B slot with (row&7)
  auto wsp = [&](int hl, int r, int cbyte) -> u16* {
    return (u16*)((char*)Ws + (size_t)(hl * 16 + r) * 4096 + (cbyte ^ ((r & 7) << 4)));
  };

  if (!isL1) {  // stage 64KB: [2][16][1024] from whh0
#pragma unroll
    for (int j = 0; j < 4; ++j) {
      const int off = tid * 64 + j * 16;
      const int plane = off >> 15;
      const int row = (off >> 11) & 15;
      const int cbyte = off & 2047;
      const u16* src = (plane ? whh0_lo : whh0_hi) + (size_t)(n0 + row) * HH + (cbyte >> 1);
      *(uint4*)wsp(plane, row, cbyte) = *(const uint4*)src;
    }
  } else {      // stage 128KB: [2][16][2048], k<1024 from wih1, k>=1024 from whh1
#pragma unroll
    for (int j = 0; j < 8; ++j) {
      const int off = tid * 128 + j * 16;
      const int plane = off >> 16;
      const int row = (off >> 12) & 15;
      const int cbyte = off & 4095;
      const int k = cbyte >> 1;
      const u16* src = (k < 1024)
          ? ((plane ? wih1_lo : wih1_hi) + (size_t)(n0 + row) * HH + k)
          : ((plane ? whh1_lo : whh1_hi) + (size_t)(n0 + row) * HH + (k - 1024));
      *(uint4*)wsp(plane, row, cbyte) = *(const uint4*)src;
    }
  }
  __syncthreads();

  const int b = (g << 4) + fr;                   // batch (B-operand col, output col)
  const int co = n0 + (kg << 2);                 // output column base (4 contiguous)
  const int koff = isL1 ? ((q < 2) ? q * 512 : (q - 2) * 512) : q * 256;  // src h col base
  const size_t hoff = (size_t)b * HH + koff + (kg << 3);
  const int cb0 = isL1 ? q * 1024 : q * 512;     // LDS row byte base of this K-slice
  float4 bias4;
  if (isL1 && q == 0) bias4 = *(const float4*)(b1 + co);

  for (int t = 0; t < nsteps; ++t) {
    const size_t obase = (size_t)t * BH;
    float4 xwv;
    if (!isL1 && q == 0) xwv = *(const float4*)(xw + obase + (size_t)b * HH + co);

    // ---- gate: one poller wave per dependency class; others spin on LDS ----
    if (!isL1) {
      if (wave == 0) {
        if (t > 0) poll_cnt(cnt0 + (t - 1));
        if (lane == 0)
          __hip_atomic_store(&gate[0], t + 1, __ATOMIC_RELAXED, __HIP_MEMORY_SCOPE_WORKGROUP);
      } else {
        while (__hip_atomic_load(&gate[0], __ATOMIC_RELAXED, __HIP_MEMORY_SCOPE_WORKGROUP) < t + 1)
          ;
      }
    } else {
      if (wave == 0) {            // class A: y0[t] (waves with q<2)
        poll_cnt(cnt0 + t);
        if (lane == 0)
          __hip_atomic_store(&gate[0], t + 1, __ATOMIC_RELAXED, __HIP_MEMORY_SCOPE_WORKGROUP);
      } else if (wave == 8) {     // class B: y1[t-1] (waves with q>=2)
        if (t > 0) poll_cnt(cnt1 + (t - 1));
        if (lane == 0)
          __hip_atomic_store(&gate[1], t + 1, __ATOMIC_RELAXED, __HIP_MEMORY_SCOPE_WORKGROUP);
      } else if (q < 2) {
        while (__hip_atomic_load(&gate[0], __ATOMIC_RELAXED, __HIP_MEMORY_SCOPE_WORKGROUP) < t + 1)
          ;
      } else {
        while (__hip_atomic_load(&gate[1], __ATOMIC_RELAXED, __HIP_MEMORY_SCOPE_WORKGROUP) < t + 1)
          ;
      }
    }
    __atomic_signal_fence(__ATOMIC_ACQUIRE);

    // ---- source pointers for this wave's K-slice ----
    const u16 *pb, *pl;
    if (!isL1) {
      const u16* hh = (t == 0) ? cin_hi : (y0hi + (size_t)(t - 1) * BH);
      const u16* hl = (t == 0) ? cin_lo : (y0lo + (size_t)(t - 1) * BH);
      pb = hh + hoff; pl = hl + hoff;
    } else if (q < 2) {
      pb = y0hi + obase + hoff; pl = y0lo + obase + hoff;
    } else {
      const u16* hh = (t == 0) ? (cin_hi + BH) : (y1hi + (size_t)(t - 1) * BH);
      const u16* hl = (t == 0) ? (cin_lo + BH) : (y1lo + (size_t)(t - 1) * BH);
      pb = hh + hoff; pl = hl + hoff;
    }

    f32x4 accs[3][2];
#pragma unroll
    for (int i = 0; i < 3; ++i)
#pragma unroll
      for (int j = 0; j < 2; ++j) accs[i][j] = (f32x4){0.f, 0.f, 0.f, 0.f};

    if (!isL1) {
#pragma unroll
      for (int kc = 0; kc < 8; ++kc) {
        bf16x8 hb  = *(const bf16x8*)(pb + kc * 32);
        bf16x8 hlv = *(const bf16x8*)(pl + kc * 32);
        const int cb = cb0 + kc * 64 + kg * 16;
        bf16x8 wh = *(const bf16x8*)wsp(0, fr, cb);
        bf16x8 wl = *(const bf16x8*)wsp(1, fr, cb);
        const int s = kc & 1;
        accs[0][s] = mfma16(wh, hb,  accs[0][s]);
        accs[1][s] = mfma16(wh, hlv, accs[1][s]);
        accs[2][s] = mfma16(wl, hb,  accs[2][s]);
      }
    } else {
#pragma unroll
      for (int kc = 0; kc < 16; ++kc) {
        bf16x8 hb  = *(const bf16x8*)(pb + kc * 32);
        bf16x8 hlv = *(const bf16x8*)(pl + kc * 32);
        const int cb = cb0 + kc * 64 + kg * 16;
        bf16x8 wh = *(const bf16x8*)wsp(0, fr, cb);
        bf16x8 wl = *(const bf16x8*)wsp(1, fr, cb);
        const int s = kc & 1;
        accs[0][s] = mfma16(wh, hb,  accs[0][s]);
        accs[1][s] = mfma16(wh, hlv, accs[1][s]);
        accs[2][s] = mfma16(wl, hb,  accs[2][s]);
      }
    }
    f32x4 accv = (accs[0][0] + accs[0][1]) + (accs[1][0] + accs[1][1]) +
                 (accs[2][0] + accs[2][1]);

    if (q != 0) red[q - 1][g][lane] = accv;
    __syncthreads();                              // barrier B

    if (q == 0) {
      accv = accv + red[0][g][lane] + red[1][g][lane] + red[2][g][lane];
      u16 hbv[4], lbv[4];
      float hv[4];
#pragma unroll
      for (int r = 0; r < 4; ++r) {
        const float s = accv[r] + (isL1 ? ((const float*)&bias4)[r] : ((const float*)&xwv)[r]);
        hv[r] = tanhf(s);
        hbv[r] = f2bf(hv[r]);
        lbv[r] = f2bf(hv[r] - bf2f(hbv[r]));
      }
      const size_t oi = obase + (size_t)b * HH + co;
      uint2 hp, lp;
      hp.x = (unsigned)hbv[0] | ((unsigned)hbv[1] << 16);
      hp.y = (unsigned)hbv[2] | ((unsigned)hbv[3] << 16);
      lp.x = (unsigned)lbv[0] | ((unsigned)lbv[1] << 16);
      lp.y = (unsigned)lbv[2] | ((unsigned)lbv[3] << 16);
      if (!isL1) { store_coh8(y0hi + oi, hp); store_coh8(y0lo + oi, lp); }
      else       { store_coh8(y1hi + oi, hp); store_coh8(y1lo + oi, lp); }
      if (t == nsteps - 1) {
        const size_t ci = (size_t)b * HH + co;
        const size_t cofs = isL1 ? (size_t)BH : 0;
        *(uint2*)(cout_hi + cofs + ci) = hp;
        *(uint2*)(cout_lo + cofs + ci) = lp;
        *(float4*)((isL1 ? hlast1 : hlast0) + ci) = (float4){hv[0], hv[1], hv[2], hv[3]};
      }
      asm volatile("s_waitcnt vmcnt(0)" ::: "memory");  // y stores reached LLC
    }
    __syncthreads();                              // barrier C
    if (tid == 0) {
      int* cp = (isL1 ? cnt1 : cnt0) + t;
      __hip_atomic_fetch_add(cp, 1, __ATOMIC_RELEASE, __HIP_MEMORY_SCOPE_AGENT);
    }
  }
}

// ---------------- host ----------------
struct Ptrs {
  u16 *wih0_hi, *wih0_lo, *whh0_hi, *whh0_lo, *wih1_hi, *wih1_lo,
      *whh1_hi, *whh1_lo, *wdec_hi, *wdec_lo;
  float *b0, *b1;
  u16 *carA_hi, *carA_lo, *carB_hi, *carB_lo;  // [2*BH] each
  int* flags;                                   // [2*T_STEPS] aggregate counters
  u16 *x_hi, *x_lo;                             // [CT*BB*CC]
  float* xw;                                    // [CT*BH]
  u16 *y0_hi, *y0_lo, *y1_hi, *y1_lo;           // [CT*BH]
  size_t total;
};

static Ptrs make_plan(char* base, int CT) {
  Ptrs p;
  size_t off = 0;
  auto take = [&](size_t bytes) -> char* {
    off = (off + 255) & ~(size_t)255;
    char* q = base + off;
    off += bytes;
    return q;
  };
  p.wih0_hi = (u16*)take((size_t)HH * CC * 2);
  p.wih0_lo = (u16*)take((size_t)HH * CC * 2);
  p.whh0_hi = (u16*)take((size_t)HH * HH * 2);
  p.whh0_lo = (u16*)take((size_t)HH * HH * 2);
  p.wih1_hi = (u16*)take((size_t)HH * HH * 2);
  p.wih1_lo = (u16*)take((size_t)HH * HH * 2);
  p.whh1_hi = (u16*)take((size_t)HH * HH * 2);
  p.whh1_lo = (u16*)take((size_t)HH * HH * 2);
  p.wdec_hi = (u16*)take((size_t)CC * HH * 2);
  p.wdec_lo = (u16*)take((size_t)CC * HH * 2);
  p.b0      = (float*)take((size_t)HH * 4);
  p.b1      = (float*)take((size_t)HH * 4);
  p.carA_hi = (u16*)take((size_t)2 * BH * 2);
  p.carA_lo = (u16*)take((size_t)2 * BH * 2);
  p.carB_hi = (u16*)take((size_t)2 * BH * 2);
  p.carB_lo = (u16*)take((size_t)2 * BH * 2);
  p.flags   = (int*)take((size_t)2 * T_STEPS * 4);
  p.x_hi    = (u16*)take((size_t)CT * BB * CC * 2);
  p.x_lo    = (u16*)take((size_t)CT * BB * CC * 2);
  p.xw      = (float*)take((size_t)CT * BH * 4);
  p.y0_hi   = (u16*)take((size_t)CT * BH * 2);
  p.y0_lo   = (u16*)take((size_t)CT * BH * 2);
  p.y1_hi   = (u16*)take((size_t)CT * BH * 2);
  p.y1_lo   = (u16*)take((size_t)CT * BH * 2);
  p.total   = off;
  return p;
}

extern "C" void kernel_launch(void* const* d_in, const int* in_sizes, int n_in,
                              void* d_out, int out_size, void* d_ws, size_t ws_size,
                              hipStream_t stream) {
  (void)in_sizes; (void)n_in; (void)out_size;
  const float* x     = (const float*)d_in[0];
  const float* h0    = (const float*)d_in[1];
  const float* w_ih0 = (const float*)d_in[2];
  const float* w_hh0 = (const float*)d_in[3];
  const float* b_ih0 = (const float*)d_in[4];
  const float* b_hh0 = (const float*)d_in[5];
  const float* w_ih1 = (const float*)d_in[6];
  const float* w_hh1 = (const float*)d_in[7];
  const float* b_ih1 = (const float*)d_in[8];
  const float* b_hh1 = (const float*)d_in[9];
  const float* w_dec = (const float*)d_in[10];
  const float* b_dec = (const float*)d_in[11];
  float* out = (float*)d_out;

  // largest chunk CT whose plan fits ws_size
  int CT = T_STEPS;
  Ptrs P = make_plan((char*)d_ws, CT);
  while (P.total > ws_size && CT > 8) {
    CT >>= 1;
    P = make_plan((char*)d_ws, CT);
  }
  if (P.total > ws_size) {
    sentinel_kernel<<<1, 1, 0, stream>>>(out, (float)ws_size);
    return;
  }
  const int NCH = T_STEPS / CT;

  hipMemsetAsync(P.flags, 0, (size_t)2 * T_STEPS * 4, stream);

  // one-time weight/bias/h0 prep
  split_kernel<<<HH * CC / 1024, 256, 0, stream>>>(w_ih0, P.wih0_hi, P.wih0_lo, HH * CC / 4);
  split_kernel<<<HH * HH / 1024, 256, 0, stream>>>(w_hh0, P.whh0_hi, P.whh0_lo, HH * HH / 4);
  split_kernel<<<HH * HH / 1024, 256, 0, stream>>>(w_ih1, P.wih1_hi, P.wih1_lo, HH * HH / 4);
  split_kernel<<<HH * HH / 1024, 256, 0, stream>>>(w_hh1, P.whh1_hi, P.whh1_lo, HH * HH / 4);
  split_kernel<<<CC * HH / 1024, 256, 0, stream>>>(w_dec, P.wdec_hi, P.wdec_lo, CC * HH / 4);
  split_kernel<<<2 * BH / 1024, 256, 0, stream>>>(h0, P.carA_hi, P.carA_lo, 2 * BH / 4);
  add_bias_kernel<<<HH / 256, 256, 0, stream>>>(b_ih0, b_hh0, P.b0, HH);
  add_bias_kernel<<<HH / 256, 256, 0, stream>>>(b_ih1, b_hh1, P.b1, HH);

  float* hlast0 = out + (size_t)TBROWS * CC;
  float* hlast1 = hlast0 + BH;

  for (int c = 0; c < NCH; ++c) {
    const int t0 = c * CT;
    const u16* cin_hi = (c & 1) ? P.carB_hi : P.carA_hi;
    const u16* cin_lo = (c & 1) ? P.carB_lo : P.carA_lo;
    u16* cout_hi = (c & 1) ? P.carA_hi : P.carB_hi;
    u16* cout_lo = (c & 1) ? P.carA_lo : P.carB_lo;

    // split x chunk
    split_kernel<<<CT * 16, 256, 0, stream>>>(x + (size_t)t0 * BB * CC, P.x_hi, P.x_lo,
                                              CT * BB * CC / 4);
    // layer-0 input projection: [CT*64, 256] @ [1024,256]^T -> xw (b0 folded in)
    gemm3<<<(CT * BB / 128) * (HH / 128), 256, 0, stream>>>(P.x_hi, P.x_lo, P.wih0_hi, P.wih0_lo,
                                                            P.b0, P.xw, CT * BB, HH, CC);
    // fused two-layer pipelined scan
    rnn_fused<<<128, 1024, 0, stream>>>(
        P.whh0_hi, P.whh0_lo, P.wih1_hi, P.wih1_lo, P.whh1_hi, P.whh1_lo,
        cin_hi, cin_lo, cout_hi, cout_lo, P.xw, P.b1,
        P.y0_hi, P.y0_lo, P.y1_hi, P.y1_lo, hlast0, hlast1,
        P.flags + t0, P.flags + T_STEPS + t0, CT);
    // decoder: [CT*64,1024] @ [256,1024]^T -> out chunk
    gemm3<<<(CT * BB / 128) * (CC / 128), 256, 0, stream>>>(P.y1_hi, P.y1_lo, P.wdec_hi, P.wdec_lo,
                                                            b_dec, out + (size_t)t0 * BB * CC,
                                                            CT * BB, CC, HH);
  }
}

// Round 9
// 9560.189 us; speedup vs baseline: 1.0803x; 1.0256x over previous
//
#include <hip/hip_runtime.h>

#define T_STEPS 512
#define BB 64
#define CC 256
#define HH 1024
#define TBROWS (T_STEPS*BB)      // 32768
#define BH (BB*HH)               // 65536
#define FLSTRIDE 32              // ints per flag line (128 B)

typedef unsigned short u16;
typedef __bf16 bf16_t;
typedef bf16_t bf16x8 __attribute__((ext_vector_type(8)));
typedef float f32x4 __attribute__((ext_vector_type(4)));

__device__ __forceinline__ f32x4 mfma16(bf16x8 a, bf16x8 b, f32x4 c) {
  return __builtin_amdgcn_mfma_f32_16x16x32_bf16(a, b, c, 0, 0, 0);
}

__device__ __forceinline__ u16 f2bf(float f) {
  unsigned u = __float_as_uint(f);
  u += 0x7fffu + ((u >> 16) & 1u);
  return (u16)(u >> 16);
}
__device__ __forceinline__ float bf2f(u16 h) {
  return __uint_as_float(((unsigned)h) << 16);
}

// coherent 8B store: write-through to LLC (agent coherence point), cross-XCD safe
__device__ __forceinline__ void store_coh8(void* p, uint2 v) {
  asm volatile("global_store_dwordx2 %0, %1, off sc0 sc1" :: "v"(p), "v"(v) : "memory");
}

// distributed-lane poll: lane w checks flag line (step, w); exits when all 64 set.
// Each flag line has ONE writer and <=2 reader lanes -> no line-steal storm.
__device__ __forceinline__ void poll_flags(const int* step_base, int lane) {
  const int* p = step_base + (size_t)(lane & 63) * FLSTRIDE;
  while (true) {
    int v = __hip_atomic_load(p, __ATOMIC_RELAXED, __HIP_MEMORY_SCOPE_AGENT);
    if (__all(v != 0)) break;
    __builtin_amdgcn_s_sleep(2);
  }
}

__global__ void sentinel_kernel(float* o, float v) { o[0] = v; }

// ---------------- split fp32 -> (hi, lo) bf16 ----------------
__global__ __launch_bounds__(256) void split_kernel(const float* __restrict__ src,
                                                    u16* __restrict__ hi,
                                                    u16* __restrict__ lo, int n4) {
  int i = blockIdx.x * 256 + threadIdx.x;
  if (i >= n4) return;
  const float4 v = ((const float4*)src)[i];
  float vv[4] = {v.x, v.y, v.z, v.w};
  u16 h[4], l[4];
#pragma unroll
  for (int j = 0; j < 4; ++j) {
    h[j] = f2bf(vv[j]);
    l[j] = f2bf(vv[j] - bf2f(h[j]));
  }
  uint2 ho, lu;
  ho.x = (unsigned)h[0] | ((unsigned)h[1] << 16);
  ho.y = (unsigned)h[2] | ((unsigned)h[3] << 16);
  lu.x = (unsigned)l[0] | ((unsigned)l[1] << 16);
  lu.y = (unsigned)l[2] | ((unsigned)l[3] << 16);
  ((uint2*)hi)[i] = ho;
  ((uint2*)lo)[i] = lu;
}

__global__ __launch_bounds__(256) void add_bias_kernel(const float* __restrict__ a,
                                                       const float* __restrict__ b,
                                                       float* __restrict__ o, int n) {
  int i = blockIdx.x * 256 + threadIdx.x;
  if (i < n) o[i] = a[i] + b[i];
}

// ---------------- split-bf16 3-pass GEMM: C[M,N] = A[M,K] @ W[N,K]^T + bias ----------------
__global__ __launch_bounds__(256) void gemm3(const u16* __restrict__ Ahi, const u16* __restrict__ Alo,
                                             const u16* __restrict__ Whi, const u16* __restrict__ Wlo,
                                             const float* __restrict__ bias,
                                             float* __restrict__ Cd,
                                             int M, int N, int K) {
  __shared__ u16 As[2][128][48];
  __shared__ u16 Bs[2][128][48];
  const int tid = threadIdx.x;
  const int nblk = N >> 7;
  const int mb = blockIdx.x / nblk;
  const int nb = blockIdx.x % nblk;
  const int m0 = mb << 7, n0 = nb << 7;
  const int lane = tid & 63, wave = tid >> 6;
  const int wm = (wave >> 1) * 64, wn = (wave & 1) * 64;
  const int fr = lane & 15, kg = lane >> 4;

  f32x4 acc[4][4];
#pragma unroll
  for (int i = 0; i < 4; ++i)
#pragma unroll
    for (int j = 0; j < 4; ++j) acc[i][j] = (f32x4){0.f, 0.f, 0.f, 0.f};

  const int sr = tid >> 1;        // 0..127
  const int sk = (tid & 1) * 16;  // 0 or 16

  for (int k0 = 0; k0 < K; k0 += 32) {
    __syncthreads();
    const size_t aoff = (size_t)(m0 + sr) * K + k0 + sk;
    *(uint4*)&As[0][sr][sk]     = *(const uint4*)(Ahi + aoff);
    *(uint4*)&As[0][sr][sk + 8] = *(const uint4*)(Ahi + aoff + 8);
    *(uint4*)&As[1][sr][sk]     = *(const uint4*)(Alo + aoff);
    *(uint4*)&As[1][sr][sk + 8] = *(const uint4*)(Alo + aoff + 8);
    const size_t woff = (size_t)(n0 + sr) * K + k0 + sk;
    *(uint4*)&Bs[0][sr][sk]     = *(const uint4*)(Whi + woff);
    *(uint4*)&Bs[0][sr][sk + 8] = *(const uint4*)(Whi + woff + 8);
    *(uint4*)&Bs[1][sr][sk]     = *(const uint4*)(Wlo + woff);
    *(uint4*)&Bs[1][sr][sk + 8] = *(const uint4*)(Wlo + woff + 8);
    __syncthreads();

    bf16x8 ah[4], al[4], bh[4], bl[4];
#pragma unroll
    for (int i = 0; i < 4; ++i) {
      ah[i] = *(const bf16x8*)&As[0][wm + i * 16 + fr][kg * 8];
      al[i] = *(const bf16x8*)&As[1][wm + i * 16 + fr][kg * 8];
      bh[i] = *(const bf16x8*)&Bs[0][wn + i * 16 + fr][kg * 8];
      bl[i] = *(const bf16x8*)&Bs[1][wn + i * 16 + fr][kg * 8];
    }
#pragma unroll
    for (int i = 0; i < 4; ++i)
#pragma unroll
      for (int j = 0; j < 4; ++j) {
        acc[i][j] = mfma16(ah[i], bh[j], acc[i][j]);
        acc[i][j] = mfma16(ah[i], bl[j], acc[i][j]);
        acc[i][j] = mfma16(al[i], bh[j], acc[i][j]);
      }
  }

#pragma unroll
  for (int j = 0; j < 4; ++j) {
    const int n = n0 + wn + j * 16 + fr;
    const float bv = bias ? bias[n] : 0.f;
#pragma unroll
    for (int i = 0; i < 4; ++i) {
#pragma unroll
      for (int r = 0; r < 4; ++r) {
        const int m = m0 + wm + i * 16 + kg * 4 + r;
        Cd[(size_t)m * N + n] = acc[i][j][r] + bv;
      }
    }
  }
}

// ---------------- fused two-layer pipelined scan ----------------
// 128 WGs x 1024 threads (16 waves = 4 K-slices x 4 batch groups), all co-resident.
// wg<64: layer 0 (K=1024). wg>=64: layer 1 (K=2048 = [W_ih1 | W_hh1]).
// r9 sync fabric: per-(t,wg) flags on PRIVATE 128B lines, plain release stores
// (no atomics RMW); poller wave polls 64 lines with distributed lanes (__all);
// producer publish via LDS completion counter (barrier C deleted, red dbuf'd).
__global__ __launch_bounds__(1024) void rnn_fused(
    const u16* __restrict__ whh0_hi, const u16* __restrict__ whh0_lo,
    const u16* __restrict__ wih1_hi, const u16* __restrict__ wih1_lo,
    const u16* __restrict__ whh1_hi, const u16* __restrict__ whh1_lo,
    const u16* __restrict__ cin_hi, const u16* __restrict__ cin_lo,    // [2*BH]
    u16* __restrict__ cout_hi, u16* __restrict__ cout_lo,              // [2*BH]
    const float* __restrict__ xw,                                      // [nsteps,B,H] (b0 included)
    const float* __restrict__ b1,                                      // [H] = b_ih1+b_hh1
    u16* __restrict__ y0hi, u16* __restrict__ y0lo,                    // [nsteps,B,H]
    u16* __restrict__ y1hi, u16* __restrict__ y1lo,                    // [nsteps,B,H]
    float* __restrict__ hlast0, float* __restrict__ hlast1,            // [B,H] f32
    int* __restrict__ flags0, int* __restrict__ flags1,                // [nsteps][64][FLSTRIDE]
    int nsteps) {
  __shared__ u16 Ws[2][16][2048];      // 128 KB (L0 uses k<1024 of each row)
  __shared__ f32x4 red[2][3][4][64];   // 24 KB, double-buffered by t&1
  __shared__ int gate[2];              // LDS release gates (step-encoded)
  __shared__ int pcnt;                 // producer-wave completion counter

  const int wg = blockIdx.x;
  const bool isL1 = wg >= 64;
  const int wl = isL1 ? wg - 64 : wg;
  const int n0 = wl << 4;
  const int tid = threadIdx.x;
  const int lane = tid & 63, wave = tid >> 6;
  const int q = wave >> 2;          // K-slice index
  const int g = wave & 3;           // batch group
  const int fr = lane & 15, kg = lane >> 4;

  if (tid < 2) gate[tid] = 0;
  if (tid == 2) pcnt = 0;

  // swizzled LDS address: row stride 4096B, XOR 16B slot with (row&7)
  auto wsp = [&](int hl, int r, int cbyte) -> u16* {
    return (u16*)((char*)Ws + (size_t)(hl * 16 + r) * 4096 + (cbyte ^ ((r & 7) << 4)));
  };

  if (!isL1) {  // stage 64KB: [2][16][1024] from whh0
#pragma unroll
    for (int j = 0; j < 4; ++j) {
      const int off = tid * 64 + j * 16;
      const int plane = off >> 15;
      const int row = (off >> 11) & 15;
      const int cbyte = off & 2047;
      const u16* src = (plane ? whh0_lo : whh0_hi) + (size_t)(n0 + row) * HH + (cbyte >> 1);
      *(uint4*)wsp(plane, row, cbyte) = *(const uint4*)src;
    }
  } else {      // stage 128KB: [2][16][2048], k<1024 from wih1, k>=1024 from whh1
#pragma unroll
    for (int j = 0; j < 8; ++j) {
      const int off = tid * 128 + j * 16;
      const int plane = off >> 16;
      const int row = (off >> 12) & 15;
      const int cbyte = off & 4095;
      const int k = cbyte >> 1;
      const u16* src = (k < 1024)
          ? ((plane ? wih1_lo : wih1_hi) + (size_t)(n0 + row) * HH + k)
          : ((plane ? whh1_lo : whh1_hi) + (size_t)(n0 + row) * HH + (k - 1024));
      *(uint4*)wsp(plane, row, cbyte) = *(const uint4*)src;
    }
  }
  __syncthreads();

  const int b = (g << 4) + fr;                   // batch (B-operand col, output col)
  const int co = n0 + (kg << 2);                 // output column base (4 contiguous)
  const int koff = isL1 ? ((q < 2) ? q * 512 : (q - 2) * 512) : q * 256;  // src h col base
  const size_t hoff = (size_t)b * HH + koff + (kg << 3);
  const int cb0 = isL1 ? q * 1024 : q * 512;     // LDS row byte base of this K-slice
  float4 bias4;
  if (isL1 && q == 0) bias4 = *(const float4*)(b1 + co);

  for (int t = 0; t < nsteps; ++t) {
    const size_t obase = (size_t)t * BH;
    float4 xwv;
    if (!isL1 && q == 0) xwv = *(const float4*)(xw + obase + (size_t)b * HH + co);

    // ---- gate: poller wave polls 64 private flag lines; others spin on LDS ----
    if (!isL1) {
      if (wave == 0) {
        if (t > 0) poll_flags(flags0 + (size_t)(t - 1) * 64 * FLSTRIDE, lane);
        if (lane == 0)
          __hip_atomic_store(&gate[0], t + 1, __ATOMIC_RELAXED, __HIP_MEMORY_SCOPE_WORKGROUP);
      } else {
        while (__hip_atomic_load(&gate[0], __ATOMIC_RELAXED, __HIP_MEMORY_SCOPE_WORKGROUP) < t + 1)
          __builtin_amdgcn_s_sleep(1);
      }
    } else {
      if (wave == 0) {            // class A: y0[t] (waves with q<2)
        poll_flags(flags0 + (size_t)t * 64 * FLSTRIDE, lane);
        if (lane == 0)
          __hip_atomic_store(&gate[0], t + 1, __ATOMIC_RELAXED, __HIP_MEMORY_SCOPE_WORKGROUP);
      } else if (wave == 8) {     // class B: y1[t-1] (waves with q>=2)
        if (t > 0) poll_flags(flags1 + (size_t)(t - 1) * 64 * FLSTRIDE, lane);
        if (lane == 0)
          __hip_atomic_store(&gate[1], t + 1, __ATOMIC_RELAXED, __HIP_MEMORY_SCOPE_WORKGROUP);
      } else if (q < 2) {
        while (__hip_atomic_load(&gate[0], __ATOMIC_RELAXED, __HIP_MEMORY_SCOPE_WORKGROUP) < t + 1)
          __builtin_amdgcn_s_sleep(1);
      } else {
        while (__hip_atomic_load(&gate[1], __ATOMIC_RELAXED, __HIP_MEMORY_SCOPE_WORKGROUP) < t + 1)
          __builtin_amdgcn_s_sleep(1);
      }
    }
    __atomic_signal_fence(__ATOMIC_ACQUIRE);

    // ---- source pointers for this wave's K-slice ----
    const u16 *pb, *pl;
    if (!isL1) {
      const u16* hh = (t == 0) ? cin_hi : (y0hi + (size_t)(t - 1) * BH);
      const u16* hl = (t == 0) ? cin_lo : (y0lo + (size_t)(t - 1) * BH);
      pb = hh + hoff; pl = hl + hoff;
    } else if (q < 2) {
      pb = y0hi + obase + hoff; pl = y0lo + obase + hoff;
    } else {
      const u16* hh = (t == 0) ? (cin_hi + BH) : (y1hi + (size_t)(t - 1) * BH);
      const u16* hl = (t == 0) ? (cin_lo + BH) : (y1lo + (size_t)(t - 1) * BH);
      pb = hh + hoff; pl = hl + hoff;
    }

    f32x4 accs[3][2];
#pragma unroll
    for (int i = 0; i < 3; ++i)
#pragma unroll
      for (int j = 0; j < 2; ++j) accs[i][j] = (f32x4){0.f, 0.f, 0.f, 0.f};

    if (!isL1) {
#pragma unroll
      for (int kc = 0; kc < 8; ++kc) {
        bf16x8 hb  = *(const bf16x8*)(pb + kc * 32);
        bf16x8 hlv = *(const bf16x8*)(pl + kc * 32);
        const int cb = cb0 + kc * 64 + kg * 16;
        bf16x8 wh = *(const bf16x8*)wsp(0, fr, cb);
        bf16x8 wl = *(const bf16x8*)wsp(1, fr, cb);
        const int s = kc & 1;
        accs[0][s] = mfma16(wh, hb,  accs[0][s]);
        accs[1][s] = mfma16(wh, hlv, accs[1][s]);
        accs[2][s] = mfma16(wl, hb,  accs[2][s]);
      }
    } else {
#pragma unroll
      for (int kc = 0; kc < 16; ++kc) {
        bf16x8 hb  = *(const bf16x8*)(pb + kc * 32);
        bf16x8 hlv = *(const bf16x8*)(pl + kc * 32);
        const int cb = cb0 + kc * 64 + kg * 16;
        bf16x8 wh = *(const bf16x8*)wsp(0, fr, cb);
        bf16x8 wl = *(const bf16x8*)wsp(1, fr, cb);
        const int s = kc & 1;
        accs[0][s] = mfma16(wh, hb,  accs[0][s]);
        accs[1][s] = mfma16(wh, hlv, accs[1][s]);
        accs[2][s] = mfma16(wl, hb,  accs[2][s]);
      }
    }
    f32x4 accv = (accs[0][0] + accs[0][1]) + (accs[1][0] + accs[1][1]) +
                 (accs[2][0] + accs[2][1]);

    if (q != 0) red[t & 1][q - 1][g][lane] = accv;
    __syncthreads();                              // barrier B (the only barrier per round)

    if (q == 0) {
      accv = accv + red[t & 1][0][g][lane] + red[t & 1][1][g][lane] + red[t & 1][2][g][lane];
      u16 hbv[4], lbv[4];
      float hv[4];
#pragma unroll
      for (int r = 0; r < 4; ++r) {
        const float s = accv[r] + (isL1 ? ((const float*)&bias4)[r] : ((const float*)&xwv)[r]);
        hv[r] = tanhf(s);
        hbv[r] = f2bf(hv[r]);
        lbv[r] = f2bf(hv[r] - bf2f(hbv[r]));
      }
      const size_t oi = obase + (size_t)b * HH + co;
      uint2 hp, lp;
      hp.x = (unsigned)hbv[0] | ((unsigned)hbv[1] << 16);
      hp.y = (unsigned)hbv[2] | ((unsigned)hbv[3] << 16);
      lp.x = (unsigned)lbv[0] | ((unsigned)lbv[1] << 16);
      lp.y = (unsigned)lbv[2] | ((unsigned)lbv[3] << 16);
      if (!isL1) { store_coh8(y0hi + oi, hp); store_coh8(y0lo + oi, lp); }
      else       { store_coh8(y1hi + oi, hp); store_coh8(y1lo + oi, lp); }
      if (t == nsteps - 1) {
        const size_t ci = (size_t)b * HH + co;
        const size_t cofs = isL1 ? (size_t)BH : 0;
        *(uint2*)(cout_hi + cofs + ci) = hp;
        *(uint2*)(cout_lo + cofs + ci) = lp;
        *(float4*)((isL1 ? hlast1 : hlast0) + ci) = (float4){hv[0], hv[1], hv[2], hv[3]};
      }
      asm volatile("s_waitcnt vmcnt(0)" ::: "memory");  // y stores reached LLC
      // publish: 4th finishing q==0 wave sets this WG's flag (plain release store)
      if (lane == 0) {
        int old = __hip_atomic_fetch_add(&pcnt, 1, __ATOMIC_ACQ_REL, __HIP_MEMORY_SCOPE_WORKGROUP);
        if (old == 3) {
          __hip_atomic_store(&pcnt, 0, __ATOMIC_RELAXED, __HIP_MEMORY_SCOPE_WORKGROUP);
          int* fp = (isL1 ? flags1 : flags0) + ((size_t)t * 64 + wl) * FLSTRIDE;
          __hip_atomic_store(fp, 1, __ATOMIC_RELEASE, __HIP_MEMORY_SCOPE_AGENT);
        }
      }
    }
    // no barrier C: red is double-buffered; next round's barrier B provides sync
  }
}

// ---------------- host ----------------
struct Ptrs {
  u16 *wih0_hi, *wih0_lo, *whh0_hi, *whh0_lo, *wih1_hi, *wih1_lo,
      *whh1_hi, *whh1_lo, *wdec_hi, *wdec_lo;
  float *b0, *b1;
  u16 *carA_hi, *carA_lo, *carB_hi, *carB_lo;  // [2*BH] each
  int* flags;                                   // [2][T_STEPS][64][FLSTRIDE]
  u16 *x_hi, *x_lo;                             // [CT*BB*CC]
  float* xw;                                    // [CT*BH]
  u16 *y0_hi, *y0_lo, *y1_hi, *y1_lo;           // [CT*BH]
  size_t total;
};

static Ptrs make_plan(char* base, int CT) {
  Ptrs p;
  size_t off = 0;
  auto take = [&](size_t bytes) -> char* {
    off = (off + 255) & ~(size_t)255;
    char* q = base + off;
    off += bytes;
    return q;
  };
  p.wih0_hi = (u16*)take((size_t)HH * CC * 2);
  p.wih0_lo = (u16*)take((size_t)HH * CC * 2);
  p.whh0_hi = (u16*)take((size_t)HH * HH * 2);
  p.whh0_lo = (u16*)take((size_t)HH * HH * 2);
  p.wih1_hi = (u16*)take((size_t)HH * HH * 2);
  p.wih1_lo = (u16*)take((size_t)HH * HH * 2);
  p.whh1_hi = (u16*)take((size_t)HH * HH * 2);
  p.whh1_lo = (u16*)take((size_t)HH * HH * 2);
  p.wdec_hi = (u16*)take((size_t)CC * HH * 2);
  p.wdec_lo = (u16*)take((size_t)CC * HH * 2);
  p.b0      = (float*)take((size_t)HH * 4);
  p.b1      = (float*)take((size_t)HH * 4);
  p.carA_hi = (u16*)take((size_t)2 * BH * 2);
  p.carA_lo = (u16*)take((size_t)2 * BH * 2);
  p.carB_hi = (u16*)take((size_t)2 * BH * 2);
  p.carB_lo = (u16*)take((size_t)2 * BH * 2);
  p.flags   = (int*)take((size_t)2 * T_STEPS * 64 * FLSTRIDE * 4);
  p.x_hi    = (u16*)take((size_t)CT * BB * CC * 2);
  p.x_lo    = (u16*)take((size_t)CT * BB * CC * 2);
  p.xw      = (float*)take((size_t)CT * BH * 4);
  p.y0_hi   = (u16*)take((size_t)CT * BH * 2);
  p.y0_lo   = (u16*)take((size_t)CT * BH * 2);
  p.y1_hi   = (u16*)take((size_t)CT * BH * 2);
  p.y1_lo   = (u16*)take((size_t)CT * BH * 2);
  p.total   = off;
  return p;
}

extern "C" void kernel_launch(void* const* d_in, const int* in_sizes, int n_in,
                              void* d_out, int out_size, void* d_ws, size_t ws_size,
                              hipStream_t stream) {
  (void)in_sizes; (void)n_in; (void)out_size;
  const float* x     = (const float*)d_in[0];
  const float* h0    = (const float*)d_in[1];
  const float* w_ih0 = (const float*)d_in[2];
  const float* w_hh0 = (const float*)d_in[3];
  const float* b_ih0 = (const float*)d_in[4];
  const float* b_hh0 = (const float*)d_in[5];
  const float* w_ih1 = (const float*)d_in[6];
  const float* w_hh1 = (const float*)d_in[7];
  const float* b_ih1 = (const float*)d_in[8];
  const float* b_hh1 = (const float*)d_in[9];
  const float* w_dec = (const float*)d_in[10];
  const float* b_dec = (const float*)d_in[11];
  float* out = (float*)d_out;

  // largest chunk CT whose plan fits ws_size
  int CT = T_STEPS;
  Ptrs P = make_plan((char*)d_ws, CT);
  while (P.total > ws_size && CT > 8) {
    CT >>= 1;
    P = make_plan((char*)d_ws, CT);
  }
  if (P.total > ws_size) {
    sentinel_kernel<<<1, 1, 0, stream>>>(out, (float)ws_size);
    return;
  }
  const int NCH = T_STEPS / CT;

  hipMemsetAsync(P.flags, 0, (size_t)2 * T_STEPS * 64 * FLSTRIDE * 4, stream);

  // one-time weight/bias/h0 prep
  split_kernel<<<HH * CC / 1024, 256, 0, stream>>>(w_ih0, P.wih0_hi, P.wih0_lo, HH * CC / 4);
  split_kernel<<<HH * HH / 1024, 256, 0, stream>>>(w_hh0, P.whh0_hi, P.whh0_lo, HH * HH / 4);
  split_kernel<<<HH * HH / 1024, 256, 0, stream>>>(w_ih1, P.wih1_hi, P.wih1_lo, HH * HH / 4);
  split_kernel<<<HH * HH / 1024, 256, 0, stream>>>(w_hh1, P.whh1_hi, P.whh1_lo, HH * HH / 4);
  split_kernel<<<CC * HH / 1024, 256, 0, stream>>>(w_dec, P.wdec_hi, P.wdec_lo, CC * HH / 4);
  split_kernel<<<2 * BH / 1024, 256, 0, stream>>>(h0, P.carA_hi, P.carA_lo, 2 * BH / 4);
  add_bias_kernel<<<HH / 256, 256, 0, stream>>>(b_ih0, b_hh0, P.b0, HH);
  add_bias_kernel<<<HH / 256, 256, 0, stream>>>(b_ih1, b_hh1, P.b1, HH);

  float* hlast0 = out + (size_t)TBROWS * CC;
  float* hlast1 = hlast0 + BH;

  for (int c = 0; c < NCH; ++c) {
    const int t0 = c * CT;
    const u16* cin_hi = (c & 1) ? P.carB_hi : P.carA_hi;
    const u16* cin_lo = (c & 1) ? P.carB_lo : P.carA_lo;
    u16* cout_hi = (c & 1) ? P.carA_hi : P.carB_hi;
    u16* cout_lo = (c & 1) ? P.carA_lo : P.carB_lo;

    // split x chunk
    split_kernel<<<CT * 16, 256, 0, stream>>>(x + (size_t)t0 * BB * CC, P.x_hi, P.x_lo,
                                              CT * BB * CC / 4);
    // layer-0 input projection: [CT*64, 256] @ [1024,256]^T -> xw (b0 folded in)
    gemm3<<<(CT * BB / 128) * (HH / 128), 256, 0, stream>>>(P.x_hi, P.x_lo, P.wih0_hi, P.wih0_lo,
                                                            P.b0, P.xw, CT * BB, HH, CC);
    // fused two-layer pipelined scan
    rnn_fused<<<128, 1024, 0, stream>>>(
        P.whh0_hi, P.whh0_lo, P.wih1_hi, P.wih1_lo, P.whh1_hi, P.whh1_lo,
        cin_hi, cin_lo, cout_hi, cout_lo, P.xw, P.b1,
        P.y0_hi, P.y0_lo, P.y1_hi, P.y1_lo, hlast0, hlast1,
        P.flags + (size_t)t0 * 64 * FLSTRIDE,
        P.flags + (size_t)(T_STEPS + t0) * 64 * FLSTRIDE, CT);
    // decoder: [CT*64,1024] @ [256,1024]^T -> out chunk
    gemm3<<<(CT * BB / 128) * (CC / 128), 256, 0, stream>>>(P.y1_hi, P.y1_lo, P.wdec_hi, P.wdec_lo,
                                                            b_dec, out + (size_t)t0 * BB * CC,
                                                            CT * BB, CC, HH);
  }
}

// Round 10
// 5508.110 us; speedup vs baseline: 1.8751x; 1.7357x over previous
//
#include <hip/hip_runtime.h>

#define T_STEPS 512
#define BB 64
#define CC 256
#define HH 1024
#define TBROWS (T_STEPS*BB)      // 32768
#define BH (BB*HH)               // 65536
#define FLSTRIDE 32              // ints per flag line (128 B)

typedef unsigned short u16;
typedef _Float16 f16;
typedef f16 f16x8 __attribute__((ext_vector_type(8)));
typedef float f32x4 __attribute__((ext_vector_type(4)));

__device__ __forceinline__ f32x4 mfma16h(f16x8 a, f16x8 b, f32x4 c) {
  return __builtin_amdgcn_mfma_f32_16x16x32_f16(a, b, c, 0, 0, 0);
}

__device__ __forceinline__ u16 f2h_bits(float f) {
  return __builtin_bit_cast(unsigned short, (f16)f);
}

// coherent 8B store: write-through to LLC (agent coherence point), cross-XCD safe
__device__ __forceinline__ void store_coh8(void* p, uint2 v) {
  asm volatile("global_store_dwordx2 %0, %1, off sc0 sc1" :: "v"(p), "v"(v) : "memory");
}

// distributed-lane poll: lane w checks flag line (step, w); exits when all 64 set.
__device__ __forceinline__ void poll_flags(const int* step_base, int lane) {
  const int* p = step_base + (size_t)(lane & 63) * FLSTRIDE;
  while (true) {
    int v = __hip_atomic_load(p, __ATOMIC_RELAXED, __HIP_MEMORY_SCOPE_AGENT);
    if (__all(v != 0)) break;
    __builtin_amdgcn_s_sleep(2);
  }
}

__global__ void sentinel_kernel(float* o, float v) { o[0] = v; }

// ---------------- fp32 -> f16 single plane ----------------
__global__ __launch_bounds__(256) void cvt_h(const float* __restrict__ src,
                                             u16* __restrict__ dst, int n4) {
  int i = blockIdx.x * 256 + threadIdx.x;
  if (i >= n4) return;
  const float4 v = ((const float4*)src)[i];
  float vv[4] = {v.x, v.y, v.z, v.w};
  uint2 o;
  o.x = (unsigned)f2h_bits(vv[0]) | ((unsigned)f2h_bits(vv[1]) << 16);
  o.y = (unsigned)f2h_bits(vv[2]) | ((unsigned)f2h_bits(vv[3]) << 16);
  ((uint2*)dst)[i] = o;
}

// ---------------- fp32 -> f16 hi + f16 (lo*2048) ----------------
__global__ __launch_bounds__(256) void split_h(const float* __restrict__ src,
                                               u16* __restrict__ hi,
                                               u16* __restrict__ lo, int n4) {
  int i = blockIdx.x * 256 + threadIdx.x;
  if (i >= n4) return;
  const float4 v = ((const float4*)src)[i];
  float vv[4] = {v.x, v.y, v.z, v.w};
  u16 h[4], l[4];
#pragma unroll
  for (int j = 0; j < 4; ++j) {
    f16 hf = (f16)vv[j];
    h[j] = __builtin_bit_cast(unsigned short, hf);
    l[j] = f2h_bits((vv[j] - (float)hf) * 2048.0f);
  }
  uint2 ho, lu;
  ho.x = (unsigned)h[0] | ((unsigned)h[1] << 16);
  ho.y = (unsigned)h[2] | ((unsigned)h[3] << 16);
  lu.x = (unsigned)l[0] | ((unsigned)l[1] << 16);
  lu.y = (unsigned)l[2] | ((unsigned)l[3] << 16);
  ((uint2*)hi)[i] = ho;
  ((uint2*)lo)[i] = lu;
}

__global__ __launch_bounds__(256) void add_bias_kernel(const float* __restrict__ a,
                                                       const float* __restrict__ b,
                                                       float* __restrict__ o, int n) {
  int i = blockIdx.x * 256 + threadIdx.x;
  if (i < n) o[i] = a[i] + b[i];
}

// ---------------- f16 GEMM: C[M,N] = A[M,K](f16) @ W[N,K](f16)^T + bias ----------------
__global__ __launch_bounds__(256) void gemmh(const u16* __restrict__ Ah,
                                             const u16* __restrict__ Wh,
                                             const float* __restrict__ bias,
                                             float* __restrict__ Cd,
                                             int M, int N, int K) {
  __shared__ u16 As[128][48];
  __shared__ u16 Bs[128][48];
  const int tid = threadIdx.x;
  const int nblk = N >> 7;
  const int mb = blockIdx.x / nblk;
  const int nb = blockIdx.x % nblk;
  const int m0 = mb << 7, n0 = nb << 7;
  const int lane = tid & 63, wave = tid >> 6;
  const int wm = (wave >> 1) * 64, wn = (wave & 1) * 64;
  const int fr = lane & 15, kg = lane >> 4;

  f32x4 acc[4][4];
#pragma unroll
  for (int i = 0; i < 4; ++i)
#pragma unroll
    for (int j = 0; j < 4; ++j) acc[i][j] = (f32x4){0.f, 0.f, 0.f, 0.f};

  const int sr = tid >> 1;        // 0..127
  const int sk = (tid & 1) * 16;  // 0 or 16

  for (int k0 = 0; k0 < K; k0 += 32) {
    __syncthreads();
    const size_t aoff = (size_t)(m0 + sr) * K + k0 + sk;
    *(uint4*)&As[sr][sk]     = *(const uint4*)(Ah + aoff);
    *(uint4*)&As[sr][sk + 8] = *(const uint4*)(Ah + aoff + 8);
    const size_t woff = (size_t)(n0 + sr) * K + k0 + sk;
    *(uint4*)&Bs[sr][sk]     = *(const uint4*)(Wh + woff);
    *(uint4*)&Bs[sr][sk + 8] = *(const uint4*)(Wh + woff + 8);
    __syncthreads();

    f16x8 ah[4], bh[4];
#pragma unroll
    for (int i = 0; i < 4; ++i) {
      ah[i] = *(const f16x8*)&As[wm + i * 16 + fr][kg * 8];
      bh[i] = *(const f16x8*)&Bs[wn + i * 16 + fr][kg * 8];
    }
#pragma unroll
    for (int i = 0; i < 4; ++i)
#pragma unroll
      for (int j = 0; j < 4; ++j)
        acc[i][j] = mfma16h(ah[i], bh[j], acc[i][j]);
  }

#pragma unroll
  for (int j = 0; j < 4; ++j) {
    const int n = n0 + wn + j * 16 + fr;
    const float bv = bias ? bias[n] : 0.f;
#pragma unroll
    for (int i = 0; i < 4; ++i) {
#pragma unroll
      for (int r = 0; r < 4; ++r) {
        const int m = m0 + wm + i * 16 + kg * 4 + r;
        Cd[(size_t)m * N + n] = acc[i][j][r] + bv;
      }
    }
  }
}

// ---------------- fused two-layer pipelined scan (f16 broadcast) ----------------
// 128 WGs x 1024 threads (16 waves = 4 K-slices x 4 batch groups), all co-resident.
// wg<64: layer 0 (K=1024). wg>=64: layer 1 (K=2048 = [W_ih1 | W_hh1]).
// r10: h transmitted as SINGLE f16 plane (halves broadcast); W in LDS as f16 hi +
// f16 lo*2048 (separate acc chain, scaled 1/2048 at combine); h loads issued as
// asm batches of 8 global_load_dwordx4 + one vmcnt(0) + sched_barrier (guaranteed
// 8 outstanding/wave; compiler defeated C++-level prefetch in r7).
__global__ __launch_bounds__(1024) void rnn_fused(
    const u16* __restrict__ whh0_hi, const u16* __restrict__ whh0_lo,
    const u16* __restrict__ wih1_hi, const u16* __restrict__ wih1_lo,
    const u16* __restrict__ whh1_hi, const u16* __restrict__ whh1_lo,
    const u16* __restrict__ cin, u16* __restrict__ cout,               // [2*BH] f16
    const float* __restrict__ xw,                                      // [nsteps,B,H] (b0 included)
    const float* __restrict__ b1,                                      // [H] = b_ih1+b_hh1
    u16* __restrict__ y0, u16* __restrict__ y1,                        // [nsteps,B,H] f16
    float* __restrict__ hlast0, float* __restrict__ hlast1,            // [B,H] f32
    int* __restrict__ flags0, int* __restrict__ flags1,                // [nsteps][64][FLSTRIDE]
    int nsteps) {
  __shared__ u16 Ws[2][16][2048];      // 128 KB f16 (L0 uses k<1024 of each row)
  __shared__ f32x4 red[2][3][4][64];   // 24 KB, double-buffered by t&1
  __shared__ int gate[2];              // LDS release gates (step-encoded)
  __shared__ int pcnt;                 // producer-wave completion counter

  const int wg = blockIdx.x;
  const bool isL1 = wg >= 64;
  const int wl = isL1 ? wg - 64 : wg;
  const int n0 = wl << 4;
  const int tid = threadIdx.x;
  const int lane = tid & 63, wave = tid >> 6;
  const int q = wave >> 2;          // K-slice index
  const int g = wave & 3;           // batch group
  const int fr = lane & 15, kg = lane >> 4;

  if (tid < 2) gate[tid] = 0;
  if (tid == 2) pcnt = 0;

  // swizzled LDS address: row stride 4096B, XOR 16B slot with (row&7)
  auto wsp = [&](int hl, int r, int cbyte) -> u16* {
    return (u16*)((char*)Ws + (size_t)(hl * 16 + r) * 4096 + (cbyte ^ ((r & 7) << 4)));
  };

  if (!isL1) {  // stage 64KB: [2][16][1024] f16 from whh0 hi/lo
#pragma unroll
    for (int j = 0; j < 4; ++j) {
      const int off = tid * 64 + j * 16;
      const int plane = off >> 15;
      const int row = (off >> 11) & 15;
      const int cbyte = off & 2047;
      const u16* src = (plane ? whh0_lo : whh0_hi) + (size_t)(n0 + row) * HH + (cbyte >> 1);
      *(uint4*)wsp(plane, row, cbyte) = *(const uint4*)src;
    }
  } else {      // stage 128KB: [2][16][2048], k<1024 from wih1, k>=1024 from whh1
#pragma unroll
    for (int j = 0; j < 8; ++j) {
      const int off = tid * 128 + j * 16;
      const int plane = off >> 16;
      const int row = (off >> 12) & 15;
      const int cbyte = off & 4095;
      const int k = cbyte >> 1;
      const u16* src = (k < 1024)
          ? ((plane ? wih1_lo : wih1_hi) + (size_t)(n0 + row) * HH + k)
          : ((plane ? whh1_lo : whh1_hi) + (size_t)(n0 + row) * HH + (k - 1024));
      *(uint4*)wsp(plane, row, cbyte) = *(const uint4*)src;
    }
  }
  __syncthreads();

  const int b = (g << 4) + fr;                   // batch (B-operand col, output col)
  const int co = n0 + (kg << 2);                 // output column base (4 contiguous)
  const int koff = isL1 ? ((q < 2) ? q * 512 : (q - 2) * 512) : q * 256;  // src h col base
  const size_t hoff = (size_t)b * HH + koff + (kg << 3);
  const int cb0 = isL1 ? q * 1024 : q * 512;     // LDS row byte base of this K-slice
  float4 bias4;
  if (isL1 && q == 0) bias4 = *(const float4*)(b1 + co);

  for (int t = 0; t < nsteps; ++t) {
    const size_t obase = (size_t)t * BH;
    float4 xwv;
    if (!isL1 && q == 0) xwv = *(const float4*)(xw + obase + (size_t)b * HH + co);

    // ---- gate: poller wave polls 64 private flag lines; others spin on LDS ----
    if (!isL1) {
      if (wave == 0) {
        if (t > 0) poll_flags(flags0 + (size_t)(t - 1) * 64 * FLSTRIDE, lane);
        if (lane == 0)
          __hip_atomic_store(&gate[0], t + 1, __ATOMIC_RELAXED, __HIP_MEMORY_SCOPE_WORKGROUP);
      } else {
        while (__hip_atomic_load(&gate[0], __ATOMIC_RELAXED, __HIP_MEMORY_SCOPE_WORKGROUP) < t + 1)
          __builtin_amdgcn_s_sleep(1);
      }
    } else {
      if (wave == 0) {            // class A: y0[t] (waves with q<2)
        poll_flags(flags0 + (size_t)t * 64 * FLSTRIDE, lane);
        if (lane == 0)
          __hip_atomic_store(&gate[0], t + 1, __ATOMIC_RELAXED, __HIP_MEMORY_SCOPE_WORKGROUP);
      } else if (wave == 8) {     // class B: y1[t-1] (waves with q>=2)
        if (t > 0) poll_flags(flags1 + (size_t)(t - 1) * 64 * FLSTRIDE, lane);
        if (lane == 0)
          __hip_atomic_store(&gate[1], t + 1, __ATOMIC_RELAXED, __HIP_MEMORY_SCOPE_WORKGROUP);
      } else if (q < 2) {
        while (__hip_atomic_load(&gate[0], __ATOMIC_RELAXED, __HIP_MEMORY_SCOPE_WORKGROUP) < t + 1)
          __builtin_amdgcn_s_sleep(1);
      } else {
        while (__hip_atomic_load(&gate[1], __ATOMIC_RELAXED, __HIP_MEMORY_SCOPE_WORKGROUP) < t + 1)
          __builtin_amdgcn_s_sleep(1);
      }
    }
    __atomic_signal_fence(__ATOMIC_ACQUIRE);

    // ---- source pointer for this wave's K-slice (single f16 plane) ----
    const u16* pb;
    if (!isL1) {
      pb = ((t == 0) ? cin : (y0 + (size_t)(t - 1) * BH)) + hoff;
    } else if (q < 2) {
      pb = y0 + obase + hoff;
    } else {
      pb = ((t == 0) ? (cin + BH) : (y1 + (size_t)(t - 1) * BH)) + hoff;
    }

    f32x4 acch[2], accl[2];
#pragma unroll
    for (int i = 0; i < 2; ++i) {
      acch[i] = (f32x4){0.f, 0.f, 0.f, 0.f};
      accl[i] = (f32x4){0.f, 0.f, 0.f, 0.f};
    }

    uint4 hv8[8];
    const int nhalf = isL1 ? 2 : 1;
#pragma unroll
    for (int half = 0; half < 2; ++half) {
      if (half < nhalf) {
        // asm-batched load phase: 8x dwordx4 in flight, one waitcnt
#pragma unroll
        for (int kc = 0; kc < 8; ++kc) {
          asm volatile("global_load_dwordx4 %0, %1, off offset:%2"
                       : "=v"(hv8[kc])
                       : "v"(pb + half * 256), "i"(kc * 64));
        }
        asm volatile("s_waitcnt vmcnt(0)" ::: "memory");
        __builtin_amdgcn_sched_barrier(0);
#pragma unroll
        for (int kc = 0; kc < 8; ++kc) {
          f16x8 hb = *(f16x8*)&hv8[kc];
          const int cb = cb0 + (half * 8 + kc) * 64 + kg * 16;
          f16x8 wh = *(const f16x8*)wsp(0, fr, cb);
          f16x8 wl = *(const f16x8*)wsp(1, fr, cb);
          const int s = kc & 1;
          acch[s] = mfma16h(wh, hb, acch[s]);
          accl[s] = mfma16h(wl, hb, accl[s]);
        }
      }
    }
    f32x4 accv = (acch[0] + acch[1]) + (accl[0] + accl[1]) * (1.0f / 2048.0f);

    if (q != 0) red[t & 1][q - 1][g][lane] = accv;
    __syncthreads();                              // barrier B (the only barrier per round)

    if (q == 0) {
      accv = accv + red[t & 1][0][g][lane] + red[t & 1][1][g][lane] + red[t & 1][2][g][lane];
      float hv[4];
      u16 qb[4];
#pragma unroll
      for (int r = 0; r < 4; ++r) {
        const float s = accv[r] + (isL1 ? ((const float*)&bias4)[r] : ((const float*)&xwv)[r]);
        hv[r] = tanhf(s);
        qb[r] = f2h_bits(hv[r]);
      }
      const size_t oi = obase + (size_t)b * HH + co;
      uint2 hp;
      hp.x = (unsigned)qb[0] | ((unsigned)qb[1] << 16);
      hp.y = (unsigned)qb[2] | ((unsigned)qb[3] << 16);
      store_coh8((isL1 ? y1 : y0) + oi, hp);
      if (t == nsteps - 1) {
        const size_t ci = (size_t)b * HH + co;
        *(uint2*)(cout + (isL1 ? (size_t)BH : 0) + ci) = hp;
        *(float4*)((isL1 ? hlast1 : hlast0) + ci) = (float4){hv[0], hv[1], hv[2], hv[3]};
      }
      asm volatile("s_waitcnt vmcnt(0)" ::: "memory");  // y stores reached LLC
      // publish: 4th finishing q==0 wave sets this WG's flag (plain release store)
      if (lane == 0) {
        int old = __hip_atomic_fetch_add(&pcnt, 1, __ATOMIC_ACQ_REL, __HIP_MEMORY_SCOPE_WORKGROUP);
        if (old == 3) {
          __hip_atomic_store(&pcnt, 0, __ATOMIC_RELAXED, __HIP_MEMORY_SCOPE_WORKGROUP);
          int* fp = (isL1 ? flags1 : flags0) + ((size_t)t * 64 + wl) * FLSTRIDE;
          __hip_atomic_store(fp, 1, __ATOMIC_RELEASE, __HIP_MEMORY_SCOPE_AGENT);
        }
      }
    }
    // no barrier C: red double-buffered; next round's barrier B provides sync
  }
}

// ---------------- host ----------------
struct Ptrs {
  u16 *wih0_h, *whh0_hi, *whh0_lo, *wih1_hi, *wih1_lo, *whh1_hi, *whh1_lo, *wdec_h;
  float *b0, *b1;
  u16 *carA, *carB;                             // [2*BH] f16 each
  int* flags;                                   // [2][T_STEPS][64][FLSTRIDE]
  u16 *x_h;                                     // [CT*BB*CC] f16
  float* xw;                                    // [CT*BH] f32
  u16 *y0, *y1;                                 // [CT*BH] f16
  size_t total;
};

static Ptrs make_plan(char* base, int CT) {
  Ptrs p;
  size_t off = 0;
  auto take = [&](size_t bytes) -> char* {
    off = (off + 255) & ~(size_t)255;
    char* q = base + off;
    off += bytes;
    return q;
  };
  p.wih0_h  = (u16*)take((size_t)HH * CC * 2);
  p.whh0_hi = (u16*)take((size_t)HH * HH * 2);
  p.whh0_lo = (u16*)take((size_t)HH * HH * 2);
  p.wih1_hi = (u16*)take((size_t)HH * HH * 2);
  p.wih1_lo = (u16*)take((size_t)HH * HH * 2);
  p.whh1_hi = (u16*)take((size_t)HH * HH * 2);
  p.whh1_lo = (u16*)take((size_t)HH * HH * 2);
  p.wdec_h  = (u16*)take((size_t)CC * HH * 2);
  p.b0      = (float*)take((size_t)HH * 4);
  p.b1      = (float*)take((size_t)HH * 4);
  p.carA    = (u16*)take((size_t)2 * BH * 2);
  p.carB    = (u16*)take((size_t)2 * BH * 2);
  p.flags   = (int*)take((size_t)2 * T_STEPS * 64 * FLSTRIDE * 4);
  p.x_h     = (u16*)take((size_t)CT * BB * CC * 2);
  p.xw      = (float*)take((size_t)CT * BH * 4);
  p.y0      = (u16*)take((size_t)CT * BH * 2);
  p.y1      = (u16*)take((size_t)CT * BH * 2);
  p.total   = off;
  return p;
}

extern "C" void kernel_launch(void* const* d_in, const int* in_sizes, int n_in,
                              void* d_out, int out_size, void* d_ws, size_t ws_size,
                              hipStream_t stream) {
  (void)in_sizes; (void)n_in; (void)out_size;
  const float* x     = (const float*)d_in[0];
  const float* h0    = (const float*)d_in[1];
  const float* w_ih0 = (const float*)d_in[2];
  const float* w_hh0 = (const float*)d_in[3];
  const float* b_ih0 = (const float*)d_in[4];
  const float* b_hh0 = (const float*)d_in[5];
  const float* w_ih1 = (const float*)d_in[6];
  const float* w_hh1 = (const float*)d_in[7];
  const float* b_ih1 = (const float*)d_in[8];
  const float* b_hh1 = (const float*)d_in[9];
  const float* w_dec = (const float*)d_in[10];
  const float* b_dec = (const float*)d_in[11];
  float* out = (float*)d_out;

  // largest chunk CT whose plan fits ws_size
  int CT = T_STEPS;
  Ptrs P = make_plan((char*)d_ws, CT);
  while (P.total > ws_size && CT > 8) {
    CT >>= 1;
    P = make_plan((char*)d_ws, CT);
  }
  if (P.total > ws_size) {
    sentinel_kernel<<<1, 1, 0, stream>>>(out, (float)ws_size);
    return;
  }
  const int NCH = T_STEPS / CT;

  hipMemsetAsync(P.flags, 0, (size_t)2 * T_STEPS * 64 * FLSTRIDE * 4, stream);

  // one-time weight/bias/h0 prep
  cvt_h<<<HH * CC / 1024, 256, 0, stream>>>(w_ih0, P.wih0_h, HH * CC / 4);
  split_h<<<HH * HH / 1024, 256, 0, stream>>>(w_hh0, P.whh0_hi, P.whh0_lo, HH * HH / 4);
  split_h<<<HH * HH / 1024, 256, 0, stream>>>(w_ih1, P.wih1_hi, P.wih1_lo, HH * HH / 4);
  split_h<<<HH * HH / 1024, 256, 0, stream>>>(w_hh1, P.whh1_hi, P.whh1_lo, HH * HH / 4);
  cvt_h<<<CC * HH / 1024, 256, 0, stream>>>(w_dec, P.wdec_h, CC * HH / 4);
  cvt_h<<<2 * BH / 1024, 256, 0, stream>>>(h0, P.carA, 2 * BH / 4);
  add_bias_kernel<<<HH / 256, 256, 0, stream>>>(b_ih0, b_hh0, P.b0, HH);
  add_bias_kernel<<<HH / 256, 256, 0, stream>>>(b_ih1, b_hh1, P.b1, HH);

  float* hlast0 = out + (size_t)TBROWS * CC;
  float* hlast1 = hlast0 + BH;

  for (int c = 0; c < NCH; ++c) {
    const int t0 = c * CT;
    const u16* cin = (c & 1) ? P.carB : P.carA;
    u16* cout = (c & 1) ? P.carA : P.carB;

    // convert x chunk to f16
    cvt_h<<<CT * BB * CC / 1024, 256, 0, stream>>>(x + (size_t)t0 * BB * CC, P.x_h,
                                                   CT * BB * CC / 4);
    // layer-0 input projection: [CT*64, 256] @ [1024,256]^T -> xw (b0 folded in)
    gemmh<<<(CT * BB / 128) * (HH / 128), 256, 0, stream>>>(P.x_h, P.wih0_h, P.b0, P.xw,
                                                            CT * BB, HH, CC);
    // fused two-layer pipelined scan
    rnn_fused<<<128, 1024, 0, stream>>>(
        P.whh0_hi, P.whh0_lo, P.wih1_hi, P.wih1_lo, P.whh1_hi, P.whh1_lo,
        cin, cout, P.xw, P.b1, P.y0, P.y1, hlast0, hlast1,
        P.flags + (size_t)t0 * 64 * FLSTRIDE,
        P.flags + (size_t)(T_STEPS + t0) * 64 * FLSTRIDE, CT);
    // decoder: [CT*64,1024] @ [256,1024]^T -> out chunk
    gemmh<<<(CT * BB / 128) * (CC / 128), 256, 0, stream>>>(P.y1, P.wdec_h, b_dec,
                                                            out + (size_t)t0 * BB * CC,
                                                            CT * BB, CC, HH);
  }
}

// Round 12
// 4962.438 us; speedup vs baseline: 2.0813x; 1.1100x over previous
//
#include <hip/hip_runtime.h>

#define T_STEPS 512
#define BB 64
#define CC 256
#define HH 1024
#define TBROWS (T_STEPS*BB)      // 32768
#define BH (BB*HH)               // 65536
#define FLSTRIDE 32              // ints per flag line (128 B)
#define RING 4                   // pA ring depth

typedef unsigned short u16;
typedef _Float16 f16;
typedef f16 f16x8 __attribute__((ext_vector_type(8)));
typedef float f32x4 __attribute__((ext_vector_type(4)));
typedef unsigned int u32x4 __attribute__((ext_vector_type(4)));
typedef unsigned int u32x2 __attribute__((ext_vector_type(2)));

__device__ __forceinline__ f32x4 mfma16h(f16x8 a, f16x8 b, f32x4 c) {
  return __builtin_amdgcn_mfma_f32_16x16x32_f16(a, b, c, 0, 0, 0);
}

__device__ __forceinline__ u16 f2h_bits(float f) {
  return __builtin_bit_cast(unsigned short, (f16)f);
}

// coherent stores: write-through to LLC (agent coherence point), cross-XCD safe
__device__ __forceinline__ void store_coh8(void* p, u32x2 v) {
  asm volatile("global_store_dwordx2 %0, %1, off sc0 sc1" :: "v"(p), "v"(v) : "memory");
}
__device__ __forceinline__ void store_coh16(void* p, u32x4 v) {
  asm volatile("global_store_dwordx4 %0, %1, off sc0 sc1" :: "v"(p), "v"(v) : "memory");
}
// coherent load (bypasses L1/L2) — for ring-reused pA slots
__device__ __forceinline__ u32x4 load_coh16(const void* p) {
  u32x4 r;
  asm volatile("global_load_dwordx4 %0, %1, off sc0 sc1" : "=v"(r) : "v"(p));
  asm volatile("s_waitcnt vmcnt(0)" ::: "memory");
  return r;
}

// distributed-lane poll: lane w checks flag line (step, w); exits when all 64 set.
__device__ __forceinline__ void poll_flags(const int* step_base, int lane) {
  const int* p = step_base + (size_t)(lane & 63) * FLSTRIDE;
  while (true) {
    int v = __hip_atomic_load(p, __ATOMIC_RELAXED, __HIP_MEMORY_SCOPE_AGENT);
    if (__all(v != 0)) break;
    __builtin_amdgcn_s_sleep(2);
  }
}
// uniform single-line poll
__device__ __forceinline__ void poll_one(const int* p) {
  while (__hip_atomic_load(p, __ATOMIC_RELAXED, __HIP_MEMORY_SCOPE_AGENT) == 0)
    __builtin_amdgcn_s_sleep(2);
}

__global__ void sentinel_kernel(float* o, float v) { o[0] = v; }

// ---------------- fp32 -> f16 single plane ----------------
__global__ __launch_bounds__(256) void cvt_h(const float* __restrict__ src,
                                             u16* __restrict__ dst, int n4) {
  int i = blockIdx.x * 256 + threadIdx.x;
  if (i >= n4) return;
  const float4 v = ((const float4*)src)[i];
  float vv[4] = {v.x, v.y, v.z, v.w};
  uint2 o;
  o.x = (unsigned)f2h_bits(vv[0]) | ((unsigned)f2h_bits(vv[1]) << 16);
  o.y = (unsigned)f2h_bits(vv[2]) | ((unsigned)f2h_bits(vv[3]) << 16);
  ((uint2*)dst)[i] = o;
}

// ---------------- fp32 -> f16 hi + f16 (lo*2048) ----------------
__global__ __launch_bounds__(256) void split_h(const float* __restrict__ src,
                                               u16* __restrict__ hi,
                                               u16* __restrict__ lo, int n4) {
  int i = blockIdx.x * 256 + threadIdx.x;
  if (i >= n4) return;
  const float4 v = ((const float4*)src)[i];
  float vv[4] = {v.x, v.y, v.z, v.w};
  u16 h[4], l[4];
#pragma unroll
  for (int j = 0; j < 4; ++j) {
    f16 hf = (f16)vv[j];
    h[j] = __builtin_bit_cast(unsigned short, hf);
    l[j] = f2h_bits((vv[j] - (float)hf) * 2048.0f);
  }
  uint2 ho, lu;
  ho.x = (unsigned)h[0] | ((unsigned)h[1] << 16);
  ho.y = (unsigned)h[2] | ((unsigned)h[3] << 16);
  lu.x = (unsigned)l[0] | ((unsigned)l[1] << 16);
  lu.y = (unsigned)l[2] | ((unsigned)l[3] << 16);
  ((uint2*)hi)[i] = ho;
  ((uint2*)lo)[i] = lu;
}

__global__ __launch_bounds__(256) void add_bias_kernel(const float* __restrict__ a,
                                                       const float* __restrict__ b,
                                                       float* __restrict__ o, int n) {
  int i = blockIdx.x * 256 + threadIdx.x;
  if (i < n) o[i] = a[i] + b[i];
}

// ---------------- f16 GEMM: C[M,N] = A[M,K](f16) @ W[N,K](f16)^T + bias ----------------
__global__ __launch_bounds__(256) void gemmh(const u16* __restrict__ Ah,
                                             const u16* __restrict__ Wh,
                                             const float* __restrict__ bias,
                                             float* __restrict__ Cd,
                                             int M, int N, int K) {
  __shared__ u16 As[128][48];
  __shared__ u16 Bs[128][48];
  const int tid = threadIdx.x;
  const int nblk = N >> 7;
  const int mb = blockIdx.x / nblk;
  const int nb = blockIdx.x % nblk;
  const int m0 = mb << 7, n0 = nb << 7;
  const int lane = tid & 63, wave = tid >> 6;
  const int wm = (wave >> 1) * 64, wn = (wave & 1) * 64;
  const int fr = lane & 15, kg = lane >> 4;

  f32x4 acc[4][4];
#pragma unroll
  for (int i = 0; i < 4; ++i)
#pragma unroll
    for (int j = 0; j < 4; ++j) acc[i][j] = (f32x4){0.f, 0.f, 0.f, 0.f};

  const int sr = tid >> 1;
  const int sk = (tid & 1) * 16;

  for (int k0 = 0; k0 < K; k0 += 32) {
    __syncthreads();
    const size_t aoff = (size_t)(m0 + sr) * K + k0 + sk;
    *(uint4*)&As[sr][sk]     = *(const uint4*)(Ah + aoff);
    *(uint4*)&As[sr][sk + 8] = *(const uint4*)(Ah + aoff + 8);
    const size_t woff = (size_t)(n0 + sr) * K + k0 + sk;
    *(uint4*)&Bs[sr][sk]     = *(const uint4*)(Wh + woff);
    *(uint4*)&Bs[sr][sk + 8] = *(const uint4*)(Wh + woff + 8);
    __syncthreads();

    f16x8 ah[4], bh[4];
#pragma unroll
    for (int i = 0; i < 4; ++i) {
      ah[i] = *(const f16x8*)&As[wm + i * 16 + fr][kg * 8];
      bh[i] = *(const f16x8*)&Bs[wn + i * 16 + fr][kg * 8];
    }
#pragma unroll
    for (int i = 0; i < 4; ++i)
#pragma unroll
      for (int j = 0; j < 4; ++j)
        acc[i][j] = mfma16h(ah[i], bh[j], acc[i][j]);
  }

#pragma unroll
  for (int j = 0; j < 4; ++j) {
    const int n = n0 + wn + j * 16 + fr;
    const float bv = bias ? bias[n] : 0.f;
#pragma unroll
    for (int i = 0; i < 4; ++i) {
#pragma unroll
      for (int r = 0; r < 4; ++r) {
        const int m = m0 + wm + i * 16 + kg * 4 + r;
        Cd[(size_t)m * N + n] = acc[i][j][r] + bv;
      }
    }
  }
}

// ---------------- fused three-family pipelined scan ----------------
// 192 WGs x 1024 threads. fam = wg>>6: 0=L0, 1=L1A (y0@W_ih1 -> pA), 2=L1B.
// Every family: K=1024, per-WG broadcast read = 128 KB/step (was 256 for L1).
// L1A writes f32 partial pA[t%RING] (4 KB/WG) + flagsA; L1B combines with
// y1[t-1]@W_hh1 and applies tanh. pA accessed with sc0/sc1 (ring reuse).
__global__ __launch_bounds__(1024) void rnn_fused(
    const u16* __restrict__ whh0_hi, const u16* __restrict__ whh0_lo,
    const u16* __restrict__ wih1_hi, const u16* __restrict__ wih1_lo,
    const u16* __restrict__ whh1_hi, const u16* __restrict__ whh1_lo,
    const u16* __restrict__ cin, u16* __restrict__ cout,               // [2*BH] f16
    const float* __restrict__ xw,                                      // [nsteps,B,H] (b0 incl.)
    const float* __restrict__ b1,                                      // [H]
    u16* __restrict__ y0, u16* __restrict__ y1,                        // [nsteps,B,H] f16
    float* __restrict__ pA,                                            // [RING][B,H] f32
    float* __restrict__ hlast0, float* __restrict__ hlast1,            // [B,H] f32
    int* __restrict__ flags0, int* __restrict__ flagsA, int* __restrict__ flags1,
    int nsteps) {
  __shared__ u16 Ws[2][16][1024];      // 64 KB f16 hi/lo planes
  __shared__ f32x4 red[2][3][4][64];   // 24 KB, double-buffered by t&1
  __shared__ int gate;                 // LDS release gate (step-encoded)
  __shared__ int pcnt;                 // producer-wave completion counter

  const int wg = blockIdx.x;
  const int fam = wg >> 6;          // 0=L0, 1=L1A, 2=L1B
  const int wl = wg & 63;
  const int n0 = wl << 4;
  const int tid = threadIdx.x;
  const int lane = tid & 63, wave = tid >> 6;
  const int q = wave >> 2;          // K-slice index
  const int g = wave & 3;           // batch group
  const int fr = lane & 15, kg = lane >> 4;

  if (tid == 0) gate = 0;
  if (tid == 2) pcnt = 0;

  // swizzled LDS address: row stride 2048B, XOR 16B slot with (row&7)
  auto wsp = [&](int hl, int r, int cbyte) -> u16* {
    return (u16*)((char*)Ws + (size_t)(hl * 16 + r) * 2048 + (cbyte ^ ((r & 7) << 4)));
  };

  {  // stage 64KB: [2][16][1024] from this family's W (hi/lo)
    const u16* whi = (fam == 0) ? whh0_hi : (fam == 1) ? wih1_hi : whh1_hi;
    const u16* wlo = (fam == 0) ? whh0_lo : (fam == 1) ? wih1_lo : whh1_lo;
#pragma unroll
    for (int j = 0; j < 4; ++j) {
      const int off = tid * 64 + j * 16;
      const int plane = off >> 15;
      const int row = (off >> 11) & 15;
      const int cbyte = off & 2047;
      const u16* src = (plane ? wlo : whi) + (size_t)(n0 + row) * HH + (cbyte >> 1);
      *(uint4*)wsp(plane, row, cbyte) = *(const uint4*)src;
    }
  }
  __syncthreads();

  const int b = (g << 4) + fr;                   // batch (B-operand col, output col)
  const int co = n0 + (kg << 2);                 // output column base (4 contiguous)
  const size_t hoff = (size_t)b * HH + q * 256 + (kg << 3);
  const int cb0 = q * 512;                       // LDS row byte base of this K-slice
  float4 bias4;
  if (fam == 1 && q == 0) bias4 = *(const float4*)(b1 + co);

  for (int t = 0; t < nsteps; ++t) {
    const size_t obase = (size_t)t * BH;
    float4 xwv;
    if (fam == 0 && q == 0) xwv = *(const float4*)(xw + obase + (size_t)b * HH + co);

    // ---- gate ----
    if (wave == 0) {
      if (fam == 0) {
        if (t > 0) poll_flags(flags0 + (size_t)(t - 1) * 64 * FLSTRIDE, lane);
      } else if (fam == 1) {
        if (t >= RING) poll_one(flags1 + ((size_t)(t - RING) * 64 + wl) * FLSTRIDE);
        poll_flags(flags0 + (size_t)t * 64 * FLSTRIDE, lane);
      } else {
        if (t > 0) poll_flags(flags1 + (size_t)(t - 1) * 64 * FLSTRIDE, lane);
      }
      if (lane == 0)
        __hip_atomic_store(&gate, t + 1, __ATOMIC_RELAXED, __HIP_MEMORY_SCOPE_WORKGROUP);
    } else {
      while (__hip_atomic_load(&gate, __ATOMIC_RELAXED, __HIP_MEMORY_SCOPE_WORKGROUP) < t + 1)
        __builtin_amdgcn_s_sleep(1);
    }
    __atomic_signal_fence(__ATOMIC_ACQUIRE);

    // ---- source pointer (single f16 plane, 128 KB broadcast) ----
    const u16* pb;
    if (fam == 0)      pb = ((t == 0) ? cin : (y0 + (size_t)(t - 1) * BH)) + hoff;
    else if (fam == 1) pb = y0 + obase + hoff;
    else               pb = ((t == 0) ? (cin + BH) : (y1 + (size_t)(t - 1) * BH)) + hoff;

    f32x4 acch[2], accl[2];
#pragma unroll
    for (int i = 0; i < 2; ++i) {
      acch[i] = (f32x4){0.f, 0.f, 0.f, 0.f};
      accl[i] = (f32x4){0.f, 0.f, 0.f, 0.f};
    }

    u32x4 hv8[8];
    // asm-batched load phase: 8x dwordx4 in flight, one waitcnt
#pragma unroll
    for (int kc = 0; kc < 8; ++kc) {
      asm volatile("global_load_dwordx4 %0, %1, off offset:%2"
                   : "=v"(hv8[kc]) : "v"(pb), "i"(kc * 64));
    }
    asm volatile("s_waitcnt vmcnt(0)" ::: "memory");
    __builtin_amdgcn_sched_barrier(0);
#pragma unroll
    for (int kc = 0; kc < 8; ++kc) {
      f16x8 hb = __builtin_bit_cast(f16x8, hv8[kc]);
      const int cb = cb0 + kc * 64 + kg * 16;
      f16x8 wh = *(const f16x8*)wsp(0, fr, cb);
      f16x8 wl = *(const f16x8*)wsp(1, fr, cb);
      const int s = kc & 1;
      acch[s] = mfma16h(wh, hb, acch[s]);
      accl[s] = mfma16h(wl, hb, accl[s]);
    }
    f32x4 accv = (acch[0] + acch[1]) + (accl[0] + accl[1]) * (1.0f / 2048.0f);

    if (q != 0) red[t & 1][q - 1][g][lane] = accv;
    __syncthreads();                              // barrier B

    if (q == 0) {
      accv = accv + red[t & 1][0][g][lane] + red[t & 1][1][g][lane] + red[t & 1][2][g][lane];

      if (fam == 1) {
        // ---- L1A epilogue: write f32 partial + b1, no tanh ----
        f32x4 o;
#pragma unroll
        for (int r = 0; r < 4; ++r) o[r] = accv[r] + ((const float*)&bias4)[r];
        store_coh16(pA + (size_t)(t & (RING - 1)) * BH + (size_t)b * HH + co,
                    __builtin_bit_cast(u32x4, o));
        asm volatile("s_waitcnt vmcnt(0)" ::: "memory");
        if (lane == 0) {
          int old = __hip_atomic_fetch_add(&pcnt, 1, __ATOMIC_ACQ_REL, __HIP_MEMORY_SCOPE_WORKGROUP);
          if (old == 3) {
            __hip_atomic_store(&pcnt, 0, __ATOMIC_RELAXED, __HIP_MEMORY_SCOPE_WORKGROUP);
            __hip_atomic_store(flagsA + ((size_t)t * 64 + wl) * FLSTRIDE, 1,
                               __ATOMIC_RELEASE, __HIP_MEMORY_SCOPE_AGENT);
          }
        }
      } else {
        float addv[4];
        if (fam == 0) {
#pragma unroll
          for (int r = 0; r < 4; ++r) addv[r] = ((const float*)&xwv)[r];
        } else {
          // L1B: wait for this WG's partial, then coherent-load it
          poll_one(flagsA + ((size_t)t * 64 + wl) * FLSTRIDE);
          u32x4 pv = load_coh16(pA + (size_t)(t & (RING - 1)) * BH + (size_t)b * HH + co);
          f32x4 pf = __builtin_bit_cast(f32x4, pv);
#pragma unroll
          for (int r = 0; r < 4; ++r) addv[r] = pf[r];
        }
        float hv[4];
        u16 qb[4];
#pragma unroll
        for (int r = 0; r < 4; ++r) {
          hv[r] = tanhf(accv[r] + addv[r]);
          qb[r] = f2h_bits(hv[r]);
        }
        const size_t oi = obase + (size_t)b * HH + co;
        u32x2 hp;
        hp.x = (unsigned)qb[0] | ((unsigned)qb[1] << 16);
        hp.y = (unsigned)qb[2] | ((unsigned)qb[3] << 16);
        store_coh8((fam == 0 ? y0 : y1) + oi, hp);
        if (t == nsteps - 1) {
          const size_t ci = (size_t)b * HH + co;
          *(u32x2*)(cout + (fam == 2 ? (size_t)BH : 0) + ci) = hp;
          *(float4*)((fam == 2 ? hlast1 : hlast0) + ci) = (float4){hv[0], hv[1], hv[2], hv[3]};
        }
        asm volatile("s_waitcnt vmcnt(0)" ::: "memory");
        if (lane == 0) {
          int old = __hip_atomic_fetch_add(&pcnt, 1, __ATOMIC_ACQ_REL, __HIP_MEMORY_SCOPE_WORKGROUP);
          if (old == 3) {
            __hip_atomic_store(&pcnt, 0, __ATOMIC_RELAXED, __HIP_MEMORY_SCOPE_WORKGROUP);
            int* fp = (fam == 0 ? flags0 : flags1) + ((size_t)t * 64 + wl) * FLSTRIDE;
            __hip_atomic_store(fp, 1, __ATOMIC_RELEASE, __HIP_MEMORY_SCOPE_AGENT);
          }
        }
      }
    }
    // famA needs barrier C (its gate doesn't include its own flags -> WAR on red)
    if (fam == 1) __syncthreads();
  }
}

// ---------------- host ----------------
struct Ptrs {
  u16 *wih0_h, *whh0_hi, *whh0_lo, *wih1_hi, *wih1_lo, *whh1_hi, *whh1_lo, *wdec_h;
  float *b0, *b1;
  u16 *carA, *carB;                             // [2*BH] f16 each
  int* flags;                                   // [3][T_STEPS][64][FLSTRIDE]
  float* pA;                                    // [RING][BH] f32
  u16 *x_h;                                     // [CT*BB*CC] f16
  float* xw;                                    // [CT*BH] f32
  u16 *y0, *y1;                                 // [CT*BH] f16
  size_t total;
};

static Ptrs make_plan(char* base, int CT) {
  Ptrs p;
  size_t off = 0;
  auto take = [&](size_t bytes) -> char* {
    off = (off + 255) & ~(size_t)255;
    char* q = base + off;
    off += bytes;
    return q;
  };
  p.wih0_h  = (u16*)take((size_t)HH * CC * 2);
  p.whh0_hi = (u16*)take((size_t)HH * HH * 2);
  p.whh0_lo = (u16*)take((size_t)HH * HH * 2);
  p.wih1_hi = (u16*)take((size_t)HH * HH * 2);
  p.wih1_lo = (u16*)take((size_t)HH * HH * 2);
  p.whh1_hi = (u16*)take((size_t)HH * HH * 2);
  p.whh1_lo = (u16*)take((size_t)HH * HH * 2);
  p.wdec_h  = (u16*)take((size_t)CC * HH * 2);
  p.b0      = (float*)take((size_t)HH * 4);
  p.b1      = (float*)take((size_t)HH * 4);
  p.carA    = (u16*)take((size_t)2 * BH * 2);
  p.carB    = (u16*)take((size_t)2 * BH * 2);
  p.flags   = (int*)take((size_t)3 * T_STEPS * 64 * FLSTRIDE * 4);
  p.pA      = (float*)take((size_t)RING * BH * 4);
  p.x_h     = (u16*)take((size_t)CT * BB * CC * 2);
  p.xw      = (float*)take((size_t)CT * BH * 4);
  p.y0      = (u16*)take((size_t)CT * BH * 2);
  p.y1      = (u16*)take((size_t)CT * BH * 2);
  p.total   = off;
  return p;
}

extern "C" void kernel_launch(void* const* d_in, const int* in_sizes, int n_in,
                              void* d_out, int out_size, void* d_ws, size_t ws_size,
                              hipStream_t stream) {
  (void)in_sizes; (void)n_in; (void)out_size;
  const float* x     = (const float*)d_in[0];
  const float* h0    = (const float*)d_in[1];
  const float* w_ih0 = (const float*)d_in[2];
  const float* w_hh0 = (const float*)d_in[3];
  const float* b_ih0 = (const float*)d_in[4];
  const float* b_hh0 = (const float*)d_in[5];
  const float* w_ih1 = (const float*)d_in[6];
  const float* w_hh1 = (const float*)d_in[7];
  const float* b_ih1 = (const float*)d_in[8];
  const float* b_hh1 = (const float*)d_in[9];
  const float* w_dec = (const float*)d_in[10];
  const float* b_dec = (const float*)d_in[11];
  float* out = (float*)d_out;

  // largest chunk CT whose plan fits ws_size
  int CT = T_STEPS;
  Ptrs P = make_plan((char*)d_ws, CT);
  while (P.total > ws_size && CT > 8) {
    CT >>= 1;
    P = make_plan((char*)d_ws, CT);
  }
  if (P.total > ws_size) {
    sentinel_kernel<<<1, 1, 0, stream>>>(out, (float)ws_size);
    return;
  }
  const int NCH = T_STEPS / CT;

  (void)hipMemsetAsync(P.flags, 0, (size_t)3 * T_STEPS * 64 * FLSTRIDE * 4, stream);

  // one-time weight/bias/h0 prep
  cvt_h<<<HH * CC / 1024, 256, 0, stream>>>(w_ih0, P.wih0_h, HH * CC / 4);
  split_h<<<HH * HH / 1024, 256, 0, stream>>>(w_hh0, P.whh0_hi, P.whh0_lo, HH * HH / 4);
  split_h<<<HH * HH / 1024, 256, 0, stream>>>(w_ih1, P.wih1_hi, P.wih1_lo, HH * HH / 4);
  split_h<<<HH * HH / 1024, 256, 0, stream>>>(w_hh1, P.whh1_hi, P.whh1_lo, HH * HH / 4);
  cvt_h<<<CC * HH / 1024, 256, 0, stream>>>(w_dec, P.wdec_h, CC * HH / 4);
  cvt_h<<<2 * BH / 1024, 256, 0, stream>>>(h0, P.carA, 2 * BH / 4);
  add_bias_kernel<<<HH / 256, 256, 0, stream>>>(b_ih0, b_hh0, P.b0, HH);
  add_bias_kernel<<<HH / 256, 256, 0, stream>>>(b_ih1, b_hh1, P.b1, HH);

  float* hlast0 = out + (size_t)TBROWS * CC;
  float* hlast1 = hlast0 + BH;

  for (int c = 0; c < NCH; ++c) {
    const int t0 = c * CT;
    const u16* cin = (c & 1) ? P.carB : P.carA;
    u16* cout = (c & 1) ? P.carA : P.carB;

    // convert x chunk to f16
    cvt_h<<<CT * BB * CC / 1024, 256, 0, stream>>>(x + (size_t)t0 * BB * CC, P.x_h,
                                                   CT * BB * CC / 4);
    // layer-0 input projection: [CT*64, 256] @ [1024,256]^T -> xw (b0 folded in)
    gemmh<<<(CT * BB / 128) * (HH / 128), 256, 0, stream>>>(P.x_h, P.wih0_h, P.b0, P.xw,
                                                            CT * BB, HH, CC);
    // fused three-family pipelined scan
    rnn_fused<<<192, 1024, 0, stream>>>(
        P.whh0_hi, P.whh0_lo, P.wih1_hi, P.wih1_lo, P.whh1_hi, P.whh1_lo,
        cin, cout, P.xw, P.b1, P.y0, P.y1, P.pA, hlast0, hlast1,
        P.flags + (size_t)t0 * 64 * FLSTRIDE,
        P.flags + (size_t)(T_STEPS + t0) * 64 * FLSTRIDE,
        P.flags + (size_t)(2 * T_STEPS + t0) * 64 * FLSTRIDE, CT);
    // decoder: [CT*64,1024] @ [256,1024]^T -> out chunk
    gemmh<<<(CT * BB / 128) * (CC / 128), 256, 0, stream>>>(P.y1, P.wdec_h, b_dec,
                                                            out + (size_t)t0 * BB * CC,
                                                            CT * BB, CC, HH);
  }
}